// Round 4
// baseline (1638.580 us; speedup 1.0000x reference)
//
#include <hip/hip_runtime.h>
#include <hip/hip_bf16.h>
#include <math.h>

#define NPTS 8192
#define CDIM 256
#define HDIM 128
#define KT   32

typedef __attribute__((ext_vector_type(8))) short bf16x8;
typedef __attribute__((ext_vector_type(4))) float f32x4;
typedef unsigned long long u64;

static __device__ __forceinline__ short f2bf(float f) {
  __hip_bfloat16 h = __float2bfloat16(f);
  return *reinterpret_cast<short*>(&h);
}

// ---------------------------------------------------------------------------
// Prep: fragment-major bf16 W2 so conv_mfma B-loads are wave-contiguous.
// ---------------------------------------------------------------------------
__global__ __launch_bounds__(256) void w2f_prep(const float* __restrict__ W2,
                                                short* __restrict__ w2f) {
  int t = blockIdx.x * 256 + threadIdx.x;   // 65536 elements
  int q = t & 7, l = (t >> 3) & 63, n = (t >> 9) & 3,
      ks = (t >> 11) & 7, w = (t >> 14) & 3;
  int k = ks * 32 + ((l >> 4) << 3) + q;
  int c = w * 64 + n * 16 + (l & 15);
  w2f[t] = f2bf(W2[k * 256 + c]);
}

// insertion step on named u64 registers (sorted ascending, b15 = largest)
#define KSTEP(s) { bool sw_ = key < b##s; u64 t_ = b##s; \
                   b##s = sw_ ? key : t_; key = sw_ ? t_ : key; }
#define KCHAIN KSTEP(0) KSTEP(1) KSTEP(2) KSTEP(3) KSTEP(4) KSTEP(5) \
               KSTEP(6) KSTEP(7) KSTEP(8) KSTEP(9) KSTEP(10) KSTEP(11) \
               KSTEP(12) KSTEP(13) KSTEP(14) KSTEP(15)
#define KINIT u64 b0=~0ULL,b1=~0ULL,b2=~0ULL,b3=~0ULL,b4=~0ULL,b5=~0ULL, \
                  b6=~0ULL,b7=~0ULL,b8=~0ULL,b9=~0ULL,b10=~0ULL,b11=~0ULL, \
                  b12=~0ULL,b13=~0ULL,b14=~0ULL,b15=~0ULL;

// ---------------------------------------------------------------------------
// kNN stage 1: bitonic-sort all points by x (exact, ties by index) in LDS.
// Single block, 1024 threads, 64KB LDS of u64 keys. Emits sorted float4
// (x,y,z,|p|^2) and the sorted->original index map.
// ---------------------------------------------------------------------------
__global__ __launch_bounds__(1024) void xsort_knn(const float* __restrict__ pos,
                                                  float4* __restrict__ spos4,
                                                  int* __restrict__ sid) {
  __shared__ u64 keys[NPTS];
  int tid = threadIdx.x;
  for (int i = tid; i < NPTS; i += 1024) {
    unsigned bits = __float_as_uint(pos[3 * i]);
    unsigned s = (bits & 0x80000000u) ? ~bits : (bits | 0x80000000u);
    keys[i] = ((u64)s << 32) | (unsigned)i;
  }
  __syncthreads();
  for (int k = 2; k <= NPTS; k <<= 1) {
    for (int j = k >> 1; j > 0; j >>= 1) {
      for (int i = tid; i < NPTS; i += 1024) {
        int ixj = i ^ j;
        if (ixj > i) {
          u64 a = keys[i], b = keys[ixj];
          bool up = ((i & k) == 0);
          if ((a > b) == up) { keys[i] = b; keys[ixj] = a; }
        }
      }
      __syncthreads();
    }
  }
  for (int s = tid; s < NPTS; s += 1024) {
    int orig = (int)(unsigned)(keys[s] & 0xffffffffu);
    float x = pos[3 * orig], y = pos[3 * orig + 1], z = pos[3 * orig + 2];
    spos4[s] = make_float4(x, y, z, x * x + y * y + z * z);
    sid[s] = orig;
  }
}

// ---------------------------------------------------------------------------
// kNN stage 2: sorted sweep. Block = 64 threads = 32 targets x {right,left}.
// Each lane expands through the x-sorted array; lane stops when
// (x_c - x_t)^2 >= current 16th-best d2 (exact bound; d15 reads as NaN until
// the heap holds 16 real keys, so pruning self-disables). Lane pairs merge
// their heaps via shfl at the end. Keys = (d2_bits<<32)|orig_idx -> exact
// lexicographic (d2, idx) order matching stable top_k.
// ---------------------------------------------------------------------------
__global__ __launch_bounds__(64) void knn_sweep(const float4* __restrict__ spos4,
                                                const int* __restrict__ sid,
                                                int* __restrict__ idx_out) {
  int lane = threadIdx.x;
  int t = lane >> 1, dir = lane & 1;      // dir 0: scan up, dir 1: scan down
  int S0 = blockIdx.x * 32;
  int st = S0 + t;
  float4 p = spos4[st];
  int orig_t = sid[st];

  KINIT
  bool done = false;

  // prefetch candidate for step 0
  int c0 = dir ? (S0 - 1) : S0;
  float4 cp = make_float4(0.f, 0.f, 0.f, 0.f);
  int cid = 0;
  if (c0 >= 0 && c0 < NPTS) { cp = spos4[c0]; cid = sid[c0]; }

  for (int step = 0;; ++step) {
    int c = dir ? (S0 - 1 - step) : (S0 + step);
    int cn = dir ? (c - 1) : (c + 1);
    float4 cc = cp; int ci = cid;
    if (cn >= 0 && cn < NPTS) { cp = spos4[cn]; cid = sid[cn]; }  // prefetch
    if (c < 0 || c >= NPTS) done = true;
    if (!done) {
      float dot = p.x * cc.x + p.y * cc.y + p.z * cc.z;
      float d2 = fmaf(-2.0f, dot, p.w + cc.w);
      d2 = fmaxf(d2, 0.0f);
      u64 key = ((u64)__float_as_uint(d2) << 32) | (unsigned)ci;
      if (key < b15) { KCHAIN }
      float dx = dir ? (p.x - cc.x) : (cc.x - p.x);
      float d15 = __uint_as_float((unsigned)(b15 >> 32));
      if (dx > 0.0f && dx * dx >= d15) done = true;   // false while d15 NaN
    }
    if (__all(done)) break;
  }

  // snapshot partner's heap, then insert (both lanes converge to same top-16)
  u64 m0 = __shfl_xor(b0, 1),  m1 = __shfl_xor(b1, 1);
  u64 m2 = __shfl_xor(b2, 1),  m3 = __shfl_xor(b3, 1);
  u64 m4 = __shfl_xor(b4, 1),  m5 = __shfl_xor(b5, 1);
  u64 m6 = __shfl_xor(b6, 1),  m7 = __shfl_xor(b7, 1);
  u64 m8 = __shfl_xor(b8, 1),  m9 = __shfl_xor(b9, 1);
  u64 m10 = __shfl_xor(b10, 1), m11 = __shfl_xor(b11, 1);
  u64 m12 = __shfl_xor(b12, 1), m13 = __shfl_xor(b13, 1);
  u64 m14 = __shfl_xor(b14, 1), m15 = __shfl_xor(b15, 1);
#define MINS(s) { u64 key = m##s; if (key < b15) { KCHAIN } }
  MINS(0) MINS(1) MINS(2) MINS(3) MINS(4) MINS(5) MINS(6) MINS(7)
  MINS(8) MINS(9) MINS(10) MINS(11) MINS(12) MINS(13) MINS(14) MINS(15)
#undef MINS

  if (dir == 0) {
    int* o = idx_out + orig_t * 16;
    o[0]=(int)(unsigned)b0;   o[1]=(int)(unsigned)b1;   o[2]=(int)(unsigned)b2;
    o[3]=(int)(unsigned)b3;   o[4]=(int)(unsigned)b4;   o[5]=(int)(unsigned)b5;
    o[6]=(int)(unsigned)b6;   o[7]=(int)(unsigned)b7;   o[8]=(int)(unsigned)b8;
    o[9]=(int)(unsigned)b9;   o[10]=(int)(unsigned)b10; o[11]=(int)(unsigned)b11;
    o[12]=(int)(unsigned)b12; o[13]=(int)(unsigned)b13; o[14]=(int)(unsigned)b14;
    o[15]=(int)(unsigned)b15;
  }
}

// ---------------------------------------------------------------------------
// fp32 GEMM: out[M][NCOLS] = act(A[M][Kdim] @ W[Kdim][NCOLS] + bias [+ pos@W1p])
// 32 rows/block (grid = 256 -> fills all CUs), micro-tile 4 x (NCOLS/32).
// ---------------------------------------------------------------------------
template <int NCOLS, int ACT, int ADDP>
__global__ __launch_bounds__(256) void gemm_bias_act(
    const float* __restrict__ A, int Kdim,
    const float* __restrict__ W,
    const float* __restrict__ bias,
    const float* __restrict__ pos,
    const float* __restrict__ W1p,
    float* __restrict__ out) {
  constexpr int NJ = NCOLS / 32;
  __shared__ float As[32][KT];
  __shared__ float Ws[KT][NCOLS];

  int tid = threadIdx.x;
  int row0 = blockIdx.x * 32;
  int tr = tid >> 5, tc = tid & 31;
  int arow = tid >> 3;
  int adb = (tid & 7) * 4;

  float acc[4][NJ];
#pragma unroll
  for (int i = 0; i < 4; ++i)
#pragma unroll
    for (int j = 0; j < NJ; ++j) acc[i][j] = 0.0f;

  int ktiles = (Kdim + KT - 1) / KT;
  for (int kt = 0; kt < ktiles; ++kt) {
    int k0 = kt * KT;
#pragma unroll
    for (int q = 0; q < 4; ++q) {
      int d = adb + q, gk = k0 + d;
      As[arow][d] = (gk < Kdim) ? A[(size_t)(row0 + arow) * Kdim + gk] : 0.0f;
    }
    constexpr int WV = (KT * NCOLS / 4) / 256;
    const float4* Wg = reinterpret_cast<const float4*>(W + (size_t)k0 * NCOLS);
#pragma unroll
    for (int q = 0; q < WV; ++q) {
      int e = q * 256 + tid;
      int d = (e * 4) / NCOLS;
      float4 v = make_float4(0.f, 0.f, 0.f, 0.f);
      if (k0 + d < Kdim) v = Wg[e];
      reinterpret_cast<float4*>(&Ws[0][0])[e] = v;
    }
    __syncthreads();
#pragma unroll 4
    for (int d = 0; d < KT; ++d) {
      float a[4];
#pragma unroll
      for (int i = 0; i < 4; ++i) a[i] = As[tr * 4 + i][d];
#pragma unroll
      for (int j = 0; j < NJ; ++j) {
        float b = Ws[d][tc + 32 * j];
#pragma unroll
        for (int i = 0; i < 4; ++i) acc[i][j] = fmaf(a[i], b, acc[i][j]);
      }
    }
    __syncthreads();
  }

  float p0[4], p1[4], p2[4];
  if constexpr (ADDP) {
#pragma unroll
    for (int i = 0; i < 4; ++i) {
      int r = row0 + tr * 4 + i;
      p0[i] = pos[3 * r]; p1[i] = pos[3 * r + 1]; p2[i] = pos[3 * r + 2];
    }
  }
#pragma unroll
  for (int j = 0; j < NJ; ++j) {
    int c = tc + 32 * j;
    float bv = bias[c];
    float w0 = 0.f, w1 = 0.f, w2 = 0.f;
    if constexpr (ADDP) { w0 = W1p[c]; w1 = W1p[256 + c]; w2 = W1p[512 + c]; }
#pragma unroll
    for (int i = 0; i < 4; ++i) {
      float v = acc[i][j] + bv;
      if constexpr (ADDP) v += p0[i] * w0 + p1[i] * w1 + p2[i] * w2;
      if (ACT == 1) v = fmaxf(v, 0.0f);
      out[(size_t)(row0 + tr * 4 + i) * NCOLS + c] = v;
    }
  }
}

// ---------------------------------------------------------------------------
// MFMA conv: block = 4 targets (64 rows = 4 x 16 nbrs) x 256 cols, K=256.
// m1 = relu(TU[j] - U[i]) staged bf16 in XOR-swizzled LDS; B from w2f
// (fragment-major, wave-contiguous 1KB loads, L2-resident).
// Epilogue: max over 16 nbr-rows (in-frag + shfl), +b2, relu.
// ---------------------------------------------------------------------------
__global__ __launch_bounds__(256) void conv_mfma(
    const float* __restrict__ TU,    // [NPTS][256] = h@W1a + b1 + pos@W1p
    const float* __restrict__ pos,
    const int* __restrict__ idx,
    const float* __restrict__ W1p,   // [3][256]
    const short* __restrict__ w2f,   // bf16 fragment-major W2
    const float* __restrict__ b2,
    float* __restrict__ hout) {
  __shared__ __align__(16) short m1s[64 * 256];
  __shared__ float Ub[4][256];
  __shared__ int js[64];

  int tid = threadIdx.x;
  int t0 = blockIdx.x * 4;
  if (tid < 64) js[tid] = idx[(t0 + (tid >> 4)) * 16 + (tid & 15)];
#pragma unroll
  for (int q = 0; q < 4; ++q) {
    int e = tid + 256 * q;
    int tg = e >> 8, c = e & 255;
    float x = pos[3 * (t0 + tg)], y = pos[3 * (t0 + tg) + 1],
          z = pos[3 * (t0 + tg) + 2];
    Ub[tg][c] = x * W1p[c] + y * W1p[256 + c] + z * W1p[512 + c];
  }
  __syncthreads();

  {
    int row = tid & 63;
    int wq = tid >> 6;
    int jrow = js[row];
    const float* TUj = TU + (size_t)jrow * 256;
    const float* Ui = &Ub[row >> 4][0];
#pragma unroll
    for (int q = 0; q < 8; ++q) {
      int c0 = wq * 8 + q * 32;
      float4 a = *reinterpret_cast<const float4*>(TUj + c0);
      float4 b = *reinterpret_cast<const float4*>(TUj + c0 + 4);
      float4 ua = *reinterpret_cast<const float4*>(Ui + c0);
      float4 ub = *reinterpret_cast<const float4*>(Ui + c0 + 4);
      bf16x8 o;
      o[0] = f2bf(fmaxf(a.x - ua.x, 0.f));
      o[1] = f2bf(fmaxf(a.y - ua.y, 0.f));
      o[2] = f2bf(fmaxf(a.z - ua.z, 0.f));
      o[3] = f2bf(fmaxf(a.w - ua.w, 0.f));
      o[4] = f2bf(fmaxf(b.x - ub.x, 0.f));
      o[5] = f2bf(fmaxf(b.y - ub.y, 0.f));
      o[6] = f2bf(fmaxf(b.z - ub.z, 0.f));
      o[7] = f2bf(fmaxf(b.w - ub.w, 0.f));
      int byte = row * 512 + c0 * 2;
      byte ^= (row & 7) << 4;                      // G4 XOR swizzle
      *reinterpret_cast<bf16x8*>(reinterpret_cast<char*>(m1s) + byte) = o;
    }
  }
  __syncthreads();

  int l = tid & 63, w = tid >> 6;
  int lhi = l >> 4, llo = l & 15;
  f32x4 zero = {0.f, 0.f, 0.f, 0.f};
  f32x4 acc[4][4];
#pragma unroll
  for (int m = 0; m < 4; ++m)
#pragma unroll
    for (int n = 0; n < 4; ++n) acc[m][n] = zero;

  const bf16x8* Wf = reinterpret_cast<const bf16x8*>(w2f);
#pragma unroll
  for (int ks = 0; ks < 8; ++ks) {
    int k0 = ks * 32;
    bf16x8 af[4], bfr[4];
#pragma unroll
    for (int m = 0; m < 4; ++m) {
      int r = m * 16 + llo;
      int byte = r * 512 + k0 * 2 + lhi * 16;
      byte ^= (r & 7) << 4;
      af[m] = *reinterpret_cast<const bf16x8*>(
          reinterpret_cast<const char*>(m1s) + byte);
    }
#pragma unroll
    for (int n = 0; n < 4; ++n)
      bfr[n] = Wf[((w * 8 + ks) * 4 + n) * 64 + l];
#pragma unroll
    for (int m = 0; m < 4; ++m)
#pragma unroll
      for (int n = 0; n < 4; ++n)
        acc[m][n] = __builtin_amdgcn_mfma_f32_16x16x32_bf16(af[m], bfr[n],
                                                            acc[m][n], 0, 0, 0);
  }

#pragma unroll
  for (int m = 0; m < 4; ++m)
#pragma unroll
    for (int n = 0; n < 4; ++n) {
      float v = fmaxf(fmaxf(acc[m][n][0], acc[m][n][1]),
                      fmaxf(acc[m][n][2], acc[m][n][3]));
      v = fmaxf(v, __shfl_xor(v, 16));
      v = fmaxf(v, __shfl_xor(v, 32));
      if (lhi == 0) {
        int c = w * 64 + n * 16 + llo;
        hout[(size_t)(t0 + m) * CDIM + c] = fmaxf(v + b2[c], 0.0f);
      }
    }
}

// ---------------------------------------------------------------------------
// Final layer: out[r] = sigmoid(h2[r] . w3 + b3); one wave per row.
// ---------------------------------------------------------------------------
__global__ __launch_bounds__(64) void final_k(const float* __restrict__ h2,
                                              const float* __restrict__ w3,
                                              const float* __restrict__ b3,
                                              float* __restrict__ out) {
  int r = blockIdx.x, l = threadIdx.x;
  float s = h2[(size_t)r * HDIM + l] * w3[l] +
            h2[(size_t)r * HDIM + 64 + l] * w3[64 + l];
#pragma unroll
  for (int o = 32; o > 0; o >>= 1) s += __shfl_down(s, o);
  if (l == 0) out[r] = 1.0f / (1.0f + expf(-(s + b3[0])));
}

extern "C" void kernel_launch(void* const* d_in, const int* in_sizes, int n_in,
                              void* d_out, int out_size, void* d_ws,
                              size_t ws_size, hipStream_t stream) {
  const float* pos   = (const float*)d_in[0];
  const float* c1_W1 = (const float*)d_in[1];
  const float* c1_b1 = (const float*)d_in[2];
  const float* c1_W2 = (const float*)d_in[3];
  const float* c1_b2 = (const float*)d_in[4];
  const float* c2_W1 = (const float*)d_in[5];
  const float* c2_b1 = (const float*)d_in[6];
  const float* c2_W2 = (const float*)d_in[7];
  const float* c2_b2 = (const float*)d_in[8];
  const float* c3_W1 = (const float*)d_in[9];
  const float* c3_b1 = (const float*)d_in[10];
  const float* c3_W2 = (const float*)d_in[11];
  const float* c3_b2 = (const float*)d_in[12];
  const float* h_W1  = (const float*)d_in[13];
  const float* h_b1  = (const float*)d_in[14];
  const float* h_W2  = (const float*)d_in[15];
  const float* h_b2  = (const float*)d_in[16];
  const float* h_W3  = (const float*)d_in[17];
  const float* h_b3  = (const float*)d_in[18];
  float* out = (float*)d_out;

  char* w = (char*)d_ws;
  const size_t MB = 1 << 20;
  int*    p_idx  = (int*)w;                         // 512KB
  float4* p_spos = (float4*)(w + 512 * 1024);       // 128KB
  int*    p_sid  = (int*)(w + 640 * 1024);          // 32KB
  short*  p_W2f1 = (short*)(w + 1 * MB);            // 128KB each
  short*  p_W2f2 = (short*)(w + 1 * MB + 128 * 1024);
  short*  p_W2f3 = (short*)(w + 1 * MB + 256 * 1024);
  float*  p_TU   = (float*)(w + 2 * MB);            // 8MB
  float*  p_hA   = (float*)(w + 10 * MB);           // 8MB
  float*  p_hB   = (float*)(w + 18 * MB);           // 8MB
  float*  p_c1   = (float*)(w + 2 * MB);            // 4MB (TU free after conv3)
  float*  p_c2   = (float*)(w + 6 * MB);            // 4MB

  // kNN: exact sorted-sweep
  xsort_knn<<<1, 1024, 0, stream>>>(pos, p_spos, p_sid);
  knn_sweep<<<NPTS / 32, 64, 0, stream>>>(p_spos, p_sid, p_idx);

  w2f_prep<<<256, 256, 0, stream>>>(c1_W2, p_W2f1);
  w2f_prep<<<256, 256, 0, stream>>>(c2_W2, p_W2f2);
  w2f_prep<<<256, 256, 0, stream>>>(c3_W2, p_W2f3);

  // conv1 (h = pos, K=3)
  gemm_bias_act<256, 0, 1><<<NPTS / 32, 256, 0, stream>>>(
      pos, 3, c1_W1, c1_b1, pos, c1_W1 + 3 * 256, p_TU);
  conv_mfma<<<NPTS / 4, 256, 0, stream>>>(p_TU, pos, p_idx, c1_W1 + 3 * 256,
                                          p_W2f1, c1_b2, p_hA);
  // conv2
  gemm_bias_act<256, 0, 1><<<NPTS / 32, 256, 0, stream>>>(
      p_hA, 256, c2_W1, c2_b1, pos, c2_W1 + 256 * 256, p_TU);
  conv_mfma<<<NPTS / 4, 256, 0, stream>>>(p_TU, pos, p_idx, c2_W1 + 256 * 256,
                                          p_W2f2, c2_b2, p_hB);
  // conv3
  gemm_bias_act<256, 0, 1><<<NPTS / 32, 256, 0, stream>>>(
      p_hB, 256, c3_W1, c3_b1, pos, c3_W1 + 256 * 256, p_TU);
  conv_mfma<<<NPTS / 4, 256, 0, stream>>>(p_TU, pos, p_idx, c3_W1 + 256 * 256,
                                          p_W2f3, c3_b2, p_hA);
  // classifier
  gemm_bias_act<128, 1, 0><<<NPTS / 32, 256, 0, stream>>>(
      p_hA, 256, h_W1, h_b1, nullptr, nullptr, p_c1);
  gemm_bias_act<128, 1, 0><<<NPTS / 32, 256, 0, stream>>>(
      p_c1, 128, h_W2, h_b2, nullptr, nullptr, p_c2);
  final_k<<<NPTS, 64, 0, stream>>>(p_c2, h_W3, h_b3, out);

  (void)in_sizes; (void)n_in; (void)out_size; (void)ws_size;
}

// Round 5
// 539.430 us; speedup vs baseline: 3.0376x; 3.0376x over previous
//
#include <hip/hip_runtime.h>
#include <hip/hip_bf16.h>
#include <math.h>

#define NPTS 8192
#define CDIM 256
#define HDIM 128
#define KT   32
#define NCH  32
#define CH   (NPTS / NCH)     // 256 candidates per chunk
#define CAP  48               // qualifier buffer slots per target

typedef __attribute__((ext_vector_type(8))) short bf16x8;
typedef __attribute__((ext_vector_type(4))) float f32x4;
typedef unsigned long long u64;

static __device__ __forceinline__ short f2bf(float f) {
  __hip_bfloat16 h = __float2bfloat16(f);
  return *reinterpret_cast<short*>(&h);
}

// Bit-exact d2 key shared by both kNN passes (all ops explicitly specified so
// both kernels compute identical bits for the same (i,j) pair).
static __device__ __forceinline__ unsigned d2key(float4 p, float4 c) {
  float dot = fmaf(p.x, c.x, fmaf(p.y, c.y, p.z * c.z));
  float d2 = fmaf(-2.0f, dot, p.w + c.w);
  return __float_as_uint(fmaxf(d2, 0.0f));
}

// ---------------------------------------------------------------------------
// Prep: pos4[i] = (x, y, z, x^2+y^2+z^2)
// ---------------------------------------------------------------------------
__global__ __launch_bounds__(256) void pos4_prep(const float* __restrict__ pos,
                                                 float4* __restrict__ pos4) {
  int i = blockIdx.x * 256 + threadIdx.x;
  float x = pos[3 * i], y = pos[3 * i + 1], z = pos[3 * i + 2];
  pos4[i] = make_float4(x, y, z, x * x + y * y + z * z);
}

// ---------------------------------------------------------------------------
// Prep: fragment-major bf16 W2 so conv_mfma B-loads are wave-contiguous.
// ---------------------------------------------------------------------------
__global__ __launch_bounds__(256) void w2f_prep(const float* __restrict__ W2,
                                                short* __restrict__ w2f) {
  int t = blockIdx.x * 256 + threadIdx.x;   // 65536 elements
  int q = t & 7, l = (t >> 3) & 63, n = (t >> 9) & 3,
      ks = (t >> 11) & 7, w = (t >> 14) & 3;
  int k = ks * 32 + ((l >> 4) << 3) + q;
  int c = w * 64 + n * 16 + (l & 15);
  w2f[t] = f2bf(W2[k * 256 + c]);
}

// u32 branchless sorting-network insert: keeps 16 smallest values, ascending.
// new[s] = min(max(old[s-1], key), old[s]); statements in descending s order
// so each reads the OLD value of [s-1].
#define U32INIT unsigned b0=~0u,b1=~0u,b2=~0u,b3=~0u,b4=~0u,b5=~0u,b6=~0u, \
                         b7=~0u,b8=~0u,b9=~0u,b10=~0u,b11=~0u,b12=~0u, \
                         b13=~0u,b14=~0u,b15=~0u;
#define U32CHAIN(key) { \
  b15 = min(max(b14, key), b15); b14 = min(max(b13, key), b14); \
  b13 = min(max(b12, key), b13); b12 = min(max(b11, key), b12); \
  b11 = min(max(b10, key), b11); b10 = min(max(b9,  key), b10); \
  b9  = min(max(b8,  key), b9);  b8  = min(max(b7,  key), b8);  \
  b7  = min(max(b6,  key), b7);  b6  = min(max(b5,  key), b6);  \
  b5  = min(max(b4,  key), b5);  b4  = min(max(b3,  key), b4);  \
  b3  = min(max(b2,  key), b3);  b2  = min(max(b1,  key), b2);  \
  b1  = min(max(b0,  key), b1);  b0  = min(key, b0); }

// u64 exact (d2,idx) insertion chain for the final select (named registers).
#define KSTEP(s) { bool sw_ = key < k##s; u64 t_ = k##s; \
                   k##s = sw_ ? key : t_; key = sw_ ? t_ : key; }
#define KCHAIN KSTEP(0) KSTEP(1) KSTEP(2) KSTEP(3) KSTEP(4) KSTEP(5) \
               KSTEP(6) KSTEP(7) KSTEP(8) KSTEP(9) KSTEP(10) KSTEP(11) \
               KSTEP(12) KSTEP(13) KSTEP(14) KSTEP(15)
#define KINIT u64 k0=~0ULL,k1=~0ULL,k2=~0ULL,k3=~0ULL,k4=~0ULL,k5=~0ULL, \
                  k6=~0ULL,k7=~0ULL,k8=~0ULL,k9=~0ULL,k10=~0ULL,k11=~0ULL, \
                  k12=~0ULL,k13=~0ULL,k14=~0ULL,k15=~0ULL;

// ---------------------------------------------------------------------------
// kNN pass 1: thread = (target i, chunk ch). 16 smallest d2 VALUES only
// (u32, branchless chain, 16 VGPRs -> full occupancy). Candidates in LDS.
// ---------------------------------------------------------------------------
__global__ __launch_bounds__(256) void knn_d2p1(const float4* __restrict__ pos4,
                                                unsigned* __restrict__ v) {
  __shared__ float4 cand[CH];
  int ch = blockIdx.x & (NCH - 1);
  int i  = (blockIdx.x >> 5) * 256 + threadIdx.x;
  cand[threadIdx.x] = pos4[ch * CH + threadIdx.x];
  __syncthreads();

  float4 p = pos4[i];
  U32INIT
  for (int jj = 0; jj < CH; ++jj) {
    unsigned key = d2key(p, cand[jj]);
    U32CHAIN(key)
  }
  unsigned* dst = v + (size_t)ch * 16 * NPTS + i;
  dst[0*(size_t)NPTS]=b0;   dst[1*(size_t)NPTS]=b1;   dst[2*(size_t)NPTS]=b2;
  dst[3*(size_t)NPTS]=b3;   dst[4*(size_t)NPTS]=b4;   dst[5*(size_t)NPTS]=b5;
  dst[6*(size_t)NPTS]=b6;   dst[7*(size_t)NPTS]=b7;   dst[8*(size_t)NPTS]=b8;
  dst[9*(size_t)NPTS]=b9;   dst[10*(size_t)NPTS]=b10; dst[11*(size_t)NPTS]=b11;
  dst[12*(size_t)NPTS]=b12; dst[13*(size_t)NPTS]=b13; dst[14*(size_t)NPTS]=b14;
  dst[15*(size_t)NPTS]=b15;
}

// ---------------------------------------------------------------------------
// kNN merge: per target, merge 32 sorted 16-lists -> exact global 16th-smallest
// d2 value T[i]. Also zeroes the pass-2 counter.
// ---------------------------------------------------------------------------
__global__ __launch_bounds__(256) void knn_merge(const unsigned* __restrict__ v,
                                                 unsigned* __restrict__ T,
                                                 unsigned* __restrict__ cnt) {
  int i = blockIdx.x * 256 + threadIdx.x;
  U32INIT
  for (int ch = 0; ch < NCH; ++ch) {
    const unsigned* src = v + (size_t)ch * 16 * NPTS + i;
#pragma unroll 1
    for (int s = 0; s < 16; ++s) {
      unsigned key = src[(size_t)s * NPTS];
      if (key >= b15) break;         // sorted chunk: rest can't contribute
      U32CHAIN(key)
    }
  }
  T[i] = b15;
  cnt[i] = 0;
}

// ---------------------------------------------------------------------------
// kNN pass 2: re-scan all candidates (identical d2key bits); collect the ~16
// qualifiers (d2 <= T) per target into a CAP-slot buffer via atomicAdd.
// ---------------------------------------------------------------------------
__global__ __launch_bounds__(256) void knn_d2p2(const float4* __restrict__ pos4,
                                                const unsigned* __restrict__ T,
                                                unsigned* __restrict__ cnt,
                                                u64* __restrict__ cbuf) {
  __shared__ float4 cand[CH];
  int ch = blockIdx.x & (NCH - 1);
  int i  = (blockIdx.x >> 5) * 256 + threadIdx.x;
  cand[threadIdx.x] = pos4[ch * CH + threadIdx.x];
  __syncthreads();

  float4 p = pos4[i];
  unsigned Ti = T[i];
  int jb = ch * CH;
  for (int jj = 0; jj < CH; ++jj) {
    unsigned key = d2key(p, cand[jj]);
    if (key <= Ti) {
      unsigned slot = atomicAdd(&cnt[i], 1u);
      if (slot < CAP)
        cbuf[(size_t)i * CAP + slot] = ((u64)key << 32) | (unsigned)(jb + jj);
    }
  }
}

// ---------------------------------------------------------------------------
// kNN select: exact lexicographic (d2, idx) top-16 over the <=CAP qualifiers.
// Matches jax.lax.top_k stable tie semantics.
// ---------------------------------------------------------------------------
__global__ __launch_bounds__(256) void knn_select(const unsigned* __restrict__ cnt,
                                                  const u64* __restrict__ cbuf,
                                                  int* __restrict__ idx_out) {
  int i = blockIdx.x * 256 + threadIdx.x;
  int c = (int)min(cnt[i], (unsigned)CAP);
  KINIT
#pragma unroll 1
  for (int q = 0; q < c; ++q) {
    u64 key = cbuf[(size_t)i * CAP + q];
    if (key < k15) { KCHAIN }
  }
  int* o = idx_out + i * 16;
  o[0]=(int)(unsigned)k0;   o[1]=(int)(unsigned)k1;   o[2]=(int)(unsigned)k2;
  o[3]=(int)(unsigned)k3;   o[4]=(int)(unsigned)k4;   o[5]=(int)(unsigned)k5;
  o[6]=(int)(unsigned)k6;   o[7]=(int)(unsigned)k7;   o[8]=(int)(unsigned)k8;
  o[9]=(int)(unsigned)k9;   o[10]=(int)(unsigned)k10; o[11]=(int)(unsigned)k11;
  o[12]=(int)(unsigned)k12; o[13]=(int)(unsigned)k13; o[14]=(int)(unsigned)k14;
  o[15]=(int)(unsigned)k15;
}

// ---------------------------------------------------------------------------
// fp32 GEMM: out[M][NCOLS] = act(A[M][Kdim] @ W[Kdim][NCOLS] + bias [+ pos@W1p])
// 32 rows/block (grid = 256 -> fills all CUs), micro-tile 4 x (NCOLS/32).
// ---------------------------------------------------------------------------
template <int NCOLS, int ACT, int ADDP>
__global__ __launch_bounds__(256) void gemm_bias_act(
    const float* __restrict__ A, int Kdim,
    const float* __restrict__ W,
    const float* __restrict__ bias,
    const float* __restrict__ pos,
    const float* __restrict__ W1p,
    float* __restrict__ out) {
  constexpr int NJ = NCOLS / 32;
  __shared__ float As[32][KT];
  __shared__ float Ws[KT][NCOLS];

  int tid = threadIdx.x;
  int row0 = blockIdx.x * 32;
  int tr = tid >> 5, tc = tid & 31;
  int arow = tid >> 3;
  int adb = (tid & 7) * 4;

  float acc[4][NJ];
#pragma unroll
  for (int i = 0; i < 4; ++i)
#pragma unroll
    for (int j = 0; j < NJ; ++j) acc[i][j] = 0.0f;

  int ktiles = (Kdim + KT - 1) / KT;
  for (int kt = 0; kt < ktiles; ++kt) {
    int k0 = kt * KT;
#pragma unroll
    for (int q = 0; q < 4; ++q) {
      int d = adb + q, gk = k0 + d;
      As[arow][d] = (gk < Kdim) ? A[(size_t)(row0 + arow) * Kdim + gk] : 0.0f;
    }
    constexpr int WV = (KT * NCOLS / 4) / 256;
    const float4* Wg = reinterpret_cast<const float4*>(W + (size_t)k0 * NCOLS);
#pragma unroll
    for (int q = 0; q < WV; ++q) {
      int e = q * 256 + tid;
      int d = (e * 4) / NCOLS;
      float4 v = make_float4(0.f, 0.f, 0.f, 0.f);
      if (k0 + d < Kdim) v = Wg[e];
      reinterpret_cast<float4*>(&Ws[0][0])[e] = v;
    }
    __syncthreads();
#pragma unroll 4
    for (int d = 0; d < KT; ++d) {
      float a[4];
#pragma unroll
      for (int i = 0; i < 4; ++i) a[i] = As[tr * 4 + i][d];
#pragma unroll
      for (int j = 0; j < NJ; ++j) {
        float b = Ws[d][tc + 32 * j];
#pragma unroll
        for (int i = 0; i < 4; ++i) acc[i][j] = fmaf(a[i], b, acc[i][j]);
      }
    }
    __syncthreads();
  }

  float p0[4], p1[4], p2[4];
  if constexpr (ADDP) {
#pragma unroll
    for (int i = 0; i < 4; ++i) {
      int r = row0 + tr * 4 + i;
      p0[i] = pos[3 * r]; p1[i] = pos[3 * r + 1]; p2[i] = pos[3 * r + 2];
    }
  }
#pragma unroll
  for (int j = 0; j < NJ; ++j) {
    int c = tc + 32 * j;
    float bv = bias[c];
    float w0 = 0.f, w1 = 0.f, w2 = 0.f;
    if constexpr (ADDP) { w0 = W1p[c]; w1 = W1p[256 + c]; w2 = W1p[512 + c]; }
#pragma unroll
    for (int i = 0; i < 4; ++i) {
      float v = acc[i][j] + bv;
      if constexpr (ADDP) v += p0[i] * w0 + p1[i] * w1 + p2[i] * w2;
      if (ACT == 1) v = fmaxf(v, 0.0f);
      out[(size_t)(row0 + tr * 4 + i) * NCOLS + c] = v;
    }
  }
}

// ---------------------------------------------------------------------------
// MFMA conv: block = 4 targets (64 rows = 4 x 16 nbrs) x 256 cols, K=256.
// m1 = relu(TU[j] - U[i]) staged bf16 in XOR-swizzled LDS; B from w2f
// (fragment-major, wave-contiguous 1KB loads, L2-resident).
// Epilogue: max over 16 nbr-rows (in-frag + shfl), +b2, relu.
// ---------------------------------------------------------------------------
__global__ __launch_bounds__(256) void conv_mfma(
    const float* __restrict__ TU,    // [NPTS][256] = h@W1a + b1 + pos@W1p
    const float* __restrict__ pos,
    const int* __restrict__ idx,
    const float* __restrict__ W1p,   // [3][256]
    const short* __restrict__ w2f,   // bf16 fragment-major W2
    const float* __restrict__ b2,
    float* __restrict__ hout) {
  __shared__ __align__(16) short m1s[64 * 256];
  __shared__ float Ub[4][256];
  __shared__ int js[64];

  int tid = threadIdx.x;
  int t0 = blockIdx.x * 4;
  if (tid < 64) js[tid] = idx[(t0 + (tid >> 4)) * 16 + (tid & 15)];
#pragma unroll
  for (int q = 0; q < 4; ++q) {
    int e = tid + 256 * q;
    int tg = e >> 8, c = e & 255;
    float x = pos[3 * (t0 + tg)], y = pos[3 * (t0 + tg) + 1],
          z = pos[3 * (t0 + tg) + 2];
    Ub[tg][c] = x * W1p[c] + y * W1p[256 + c] + z * W1p[512 + c];
  }
  __syncthreads();

  {
    int row = tid & 63;
    int wq = tid >> 6;
    int jrow = js[row];
    const float* TUj = TU + (size_t)jrow * 256;
    const float* Ui = &Ub[row >> 4][0];
#pragma unroll
    for (int q = 0; q < 8; ++q) {
      int c0 = wq * 8 + q * 32;
      float4 a = *reinterpret_cast<const float4*>(TUj + c0);
      float4 b = *reinterpret_cast<const float4*>(TUj + c0 + 4);
      float4 ua = *reinterpret_cast<const float4*>(Ui + c0);
      float4 ub = *reinterpret_cast<const float4*>(Ui + c0 + 4);
      bf16x8 o;
      o[0] = f2bf(fmaxf(a.x - ua.x, 0.f));
      o[1] = f2bf(fmaxf(a.y - ua.y, 0.f));
      o[2] = f2bf(fmaxf(a.z - ua.z, 0.f));
      o[3] = f2bf(fmaxf(a.w - ua.w, 0.f));
      o[4] = f2bf(fmaxf(b.x - ub.x, 0.f));
      o[5] = f2bf(fmaxf(b.y - ub.y, 0.f));
      o[6] = f2bf(fmaxf(b.z - ub.z, 0.f));
      o[7] = f2bf(fmaxf(b.w - ub.w, 0.f));
      int byte = row * 512 + c0 * 2;
      byte ^= (row & 7) << 4;                      // G4 XOR swizzle
      *reinterpret_cast<bf16x8*>(reinterpret_cast<char*>(m1s) + byte) = o;
    }
  }
  __syncthreads();

  int l = tid & 63, w = tid >> 6;
  int lhi = l >> 4, llo = l & 15;
  f32x4 zero = {0.f, 0.f, 0.f, 0.f};
  f32x4 acc[4][4];
#pragma unroll
  for (int m = 0; m < 4; ++m)
#pragma unroll
    for (int n = 0; n < 4; ++n) acc[m][n] = zero;

  const bf16x8* Wf = reinterpret_cast<const bf16x8*>(w2f);
#pragma unroll
  for (int ks = 0; ks < 8; ++ks) {
    int k0 = ks * 32;
    bf16x8 af[4], bfr[4];
#pragma unroll
    for (int m = 0; m < 4; ++m) {
      int r = m * 16 + llo;
      int byte = r * 512 + k0 * 2 + lhi * 16;
      byte ^= (r & 7) << 4;
      af[m] = *reinterpret_cast<const bf16x8*>(
          reinterpret_cast<const char*>(m1s) + byte);
    }
#pragma unroll
    for (int n = 0; n < 4; ++n)
      bfr[n] = Wf[((w * 8 + ks) * 4 + n) * 64 + l];
#pragma unroll
    for (int m = 0; m < 4; ++m)
#pragma unroll
      for (int n = 0; n < 4; ++n)
        acc[m][n] = __builtin_amdgcn_mfma_f32_16x16x32_bf16(af[m], bfr[n],
                                                            acc[m][n], 0, 0, 0);
  }

#pragma unroll
  for (int m = 0; m < 4; ++m)
#pragma unroll
    for (int n = 0; n < 4; ++n) {
      float v = fmaxf(fmaxf(acc[m][n][0], acc[m][n][1]),
                      fmaxf(acc[m][n][2], acc[m][n][3]));
      v = fmaxf(v, __shfl_xor(v, 16));
      v = fmaxf(v, __shfl_xor(v, 32));
      if (lhi == 0) {
        int c = w * 64 + n * 16 + llo;
        hout[(size_t)(t0 + m) * CDIM + c] = fmaxf(v + b2[c], 0.0f);
      }
    }
}

// ---------------------------------------------------------------------------
// Final layer: out[r] = sigmoid(h2[r] . w3 + b3); one wave per row.
// ---------------------------------------------------------------------------
__global__ __launch_bounds__(64) void final_k(const float* __restrict__ h2,
                                              const float* __restrict__ w3,
                                              const float* __restrict__ b3,
                                              float* __restrict__ out) {
  int r = blockIdx.x, l = threadIdx.x;
  float s = h2[(size_t)r * HDIM + l] * w3[l] +
            h2[(size_t)r * HDIM + 64 + l] * w3[64 + l];
#pragma unroll
  for (int o = 32; o > 0; o >>= 1) s += __shfl_down(s, o);
  if (l == 0) out[r] = 1.0f / (1.0f + expf(-(s + b3[0])));
}

extern "C" void kernel_launch(void* const* d_in, const int* in_sizes, int n_in,
                              void* d_out, int out_size, void* d_ws,
                              size_t ws_size, hipStream_t stream) {
  const float* pos   = (const float*)d_in[0];
  const float* c1_W1 = (const float*)d_in[1];
  const float* c1_b1 = (const float*)d_in[2];
  const float* c1_W2 = (const float*)d_in[3];
  const float* c1_b2 = (const float*)d_in[4];
  const float* c2_W1 = (const float*)d_in[5];
  const float* c2_b1 = (const float*)d_in[6];
  const float* c2_W2 = (const float*)d_in[7];
  const float* c2_b2 = (const float*)d_in[8];
  const float* c3_W1 = (const float*)d_in[9];
  const float* c3_b1 = (const float*)d_in[10];
  const float* c3_W2 = (const float*)d_in[11];
  const float* c3_b2 = (const float*)d_in[12];
  const float* h_W1  = (const float*)d_in[13];
  const float* h_b1  = (const float*)d_in[14];
  const float* h_W2  = (const float*)d_in[15];
  const float* h_b2  = (const float*)d_in[16];
  const float* h_W3  = (const float*)d_in[17];
  const float* h_b3  = (const float*)d_in[18];
  float* out = (float*)d_out;

  char* w = (char*)d_ws;
  const size_t MB = 1 << 20;
  int*      p_idx  = (int*)w;                           // 512KB
  float4*   p_pos4 = (float4*)(w + 512 * 1024);         // 128KB
  unsigned* p_T    = (unsigned*)(w + 640 * 1024);       // 32KB
  unsigned* p_cnt  = (unsigned*)(w + 672 * 1024);       // 32KB
  short*    p_W2f1 = (short*)(w + 704 * 1024);          // 128KB each
  short*    p_W2f2 = (short*)(w + 832 * 1024);
  short*    p_W2f3 = (short*)(w + 960 * 1024);
  u64*      p_cbuf = (u64*)(w + 1280 * 1024);           // 3MB (8192*48*8)
  unsigned* p_v    = (unsigned*)(w + 5 * MB);           // 16MB [5,21) knn only
  float*    p_TU   = (float*)(w + 5 * MB);              // 8MB  (after knn)
  float*    p_hA   = (float*)(w + 13 * MB);             // 8MB
  float*    p_hB   = (float*)(w + 21 * MB);             // 8MB
  float*    p_c1   = (float*)(w + 5 * MB);              // 4MB (after conv3)
  float*    p_c2   = (float*)(w + 9 * MB);              // 4MB

  // kNN: two-pass exact top-16
  pos4_prep<<<NPTS / 256, 256, 0, stream>>>(pos, p_pos4);
  knn_d2p1<<<(NPTS / 256) * NCH, 256, 0, stream>>>(p_pos4, p_v);
  knn_merge<<<NPTS / 256, 256, 0, stream>>>(p_v, p_T, p_cnt);
  knn_d2p2<<<(NPTS / 256) * NCH, 256, 0, stream>>>(p_pos4, p_T, p_cnt, p_cbuf);
  knn_select<<<NPTS / 256, 256, 0, stream>>>(p_cnt, p_cbuf, p_idx);

  w2f_prep<<<256, 256, 0, stream>>>(c1_W2, p_W2f1);
  w2f_prep<<<256, 256, 0, stream>>>(c2_W2, p_W2f2);
  w2f_prep<<<256, 256, 0, stream>>>(c3_W2, p_W2f3);

  // conv1 (h = pos, K=3)
  gemm_bias_act<256, 0, 1><<<NPTS / 32, 256, 0, stream>>>(
      pos, 3, c1_W1, c1_b1, pos, c1_W1 + 3 * 256, p_TU);
  conv_mfma<<<NPTS / 4, 256, 0, stream>>>(p_TU, pos, p_idx, c1_W1 + 3 * 256,
                                          p_W2f1, c1_b2, p_hA);
  // conv2
  gemm_bias_act<256, 0, 1><<<NPTS / 32, 256, 0, stream>>>(
      p_hA, 256, c2_W1, c2_b1, pos, c2_W1 + 256 * 256, p_TU);
  conv_mfma<<<NPTS / 4, 256, 0, stream>>>(p_TU, pos, p_idx, c2_W1 + 256 * 256,
                                          p_W2f2, c2_b2, p_hB);
  // conv3
  gemm_bias_act<256, 0, 1><<<NPTS / 32, 256, 0, stream>>>(
      p_hB, 256, c3_W1, c3_b1, pos, c3_W1 + 256 * 256, p_TU);
  conv_mfma<<<NPTS / 4, 256, 0, stream>>>(p_TU, pos, p_idx, c3_W1 + 256 * 256,
                                          p_W2f3, c3_b2, p_hA);
  // classifier
  gemm_bias_act<128, 1, 0><<<NPTS / 32, 256, 0, stream>>>(
      p_hA, 256, h_W1, h_b1, nullptr, nullptr, p_c1);
  gemm_bias_act<128, 1, 0><<<NPTS / 32, 256, 0, stream>>>(
      p_c1, 128, h_W2, h_b2, nullptr, nullptr, p_c2);
  final_k<<<NPTS, 64, 0, stream>>>(p_c2, h_W3, h_b3, out);

  (void)in_sizes; (void)n_in; (void)out_size; (void)ws_size;
}

// Round 6
// 375.482 us; speedup vs baseline: 4.3639x; 1.4366x over previous
//
#include <hip/hip_runtime.h>
#include <hip/hip_bf16.h>
#include <math.h>

#define NPTS 8192
#define CDIM 256
#define HDIM 128
#define NCH  32
#define CH   (NPTS / NCH)     // 256 candidates per chunk
#define CAP  48               // qualifier buffer slots per target

typedef __attribute__((ext_vector_type(8))) short bf16x8;
typedef __attribute__((ext_vector_type(4))) float f32x4;
typedef unsigned long long u64;

static __device__ __forceinline__ short f2bf(float f) {
  __hip_bfloat16 h = __float2bfloat16(f);
  return *reinterpret_cast<short*>(&h);
}

// median-of-3: one VALU op; med3(lo, key, hi) == min(max(lo,key),hi) for lo<=hi
static __device__ __forceinline__ unsigned umed3(unsigned a, unsigned b,
                                                 unsigned c) {
  unsigned d;
  asm("v_med3_u32 %0, %1, %2, %3" : "=v"(d) : "v"(a), "v"(b), "v"(c));
  return d;
}

// Bit-exact d2 key shared by both kNN passes.
static __device__ __forceinline__ unsigned d2key(float4 p, float4 c) {
  float dot = fmaf(p.x, c.x, fmaf(p.y, c.y, p.z * c.z));
  float d2 = fmaf(-2.0f, dot, p.w + c.w);
  return __float_as_uint(fmaxf(d2, 0.0f));
}

// ---------------------------------------------------------------------------
// Prep: pos4[i] = (x, y, z, x^2+y^2+z^2)
// ---------------------------------------------------------------------------
__global__ __launch_bounds__(256) void pos4_prep(const float* __restrict__ pos,
                                                 float4* __restrict__ pos4) {
  int i = blockIdx.x * 256 + threadIdx.x;
  float x = pos[3 * i], y = pos[3 * i + 1], z = pos[3 * i + 2];
  pos4[i] = make_float4(x, y, z, x * x + y * y + z * z);
}

// ---------------------------------------------------------------------------
// Prep: fragment-major bf16 weights. Flat index t = (((c16*KS)+ks)*64+l)*8+q;
// element (k, c) = (ks*32 + (l>>4)*8 + q, c16*16 + (l&15)). B-frag loads in
// the GEMMs are then wave-contiguous 1KB reads.
// ---------------------------------------------------------------------------
template <int KDIM, int NCOLS>
__global__ __launch_bounds__(256) void wf_prep(const float* __restrict__ W,
                                               short* __restrict__ wf) {
  int t = blockIdx.x * 256 + threadIdx.x;
  constexpr int KS = KDIM / 32;
  int q = t & 7, l = (t >> 3) & 63, F = t >> 9;
  int ks = F % KS, c16 = F / KS;
  int k = ks * 32 + ((l >> 4) << 3) + q;
  int c = c16 * 16 + (l & 15);
  wf[t] = f2bf(W[k * NCOLS + c]);
}

// u32 branchless top-16 insert: b[s] = med3(b[s-1], key, b[s]) (16 indep ops).
#define U32INIT unsigned b0=~0u,b1=~0u,b2=~0u,b3=~0u,b4=~0u,b5=~0u,b6=~0u, \
                         b7=~0u,b8=~0u,b9=~0u,b10=~0u,b11=~0u,b12=~0u, \
                         b13=~0u,b14=~0u,b15=~0u;
#define U32CHAIN(key) { \
  b15 = umed3(b14, key, b15); b14 = umed3(b13, key, b14); \
  b13 = umed3(b12, key, b13); b12 = umed3(b11, key, b12); \
  b11 = umed3(b10, key, b11); b10 = umed3(b9,  key, b10); \
  b9  = umed3(b8,  key, b9);  b8  = umed3(b7,  key, b8);  \
  b7  = umed3(b6,  key, b7);  b6  = umed3(b5,  key, b6);  \
  b5  = umed3(b4,  key, b5);  b4  = umed3(b3,  key, b4);  \
  b3  = umed3(b2,  key, b3);  b2  = umed3(b1,  key, b2);  \
  b1  = umed3(b0,  key, b1);  b0  = min(b0, key); }

// u64 exact (d2,idx) insertion chain for the final select.
#define KSTEP(s) { bool sw_ = key < k##s; u64 t_ = k##s; \
                   k##s = sw_ ? key : t_; key = sw_ ? t_ : key; }
#define KCHAIN KSTEP(0) KSTEP(1) KSTEP(2) KSTEP(3) KSTEP(4) KSTEP(5) \
               KSTEP(6) KSTEP(7) KSTEP(8) KSTEP(9) KSTEP(10) KSTEP(11) \
               KSTEP(12) KSTEP(13) KSTEP(14) KSTEP(15)
#define KINIT u64 k0=~0ULL,k1=~0ULL,k2=~0ULL,k3=~0ULL,k4=~0ULL,k5=~0ULL, \
                  k6=~0ULL,k7=~0ULL,k8=~0ULL,k9=~0ULL,k10=~0ULL,k11=~0ULL, \
                  k12=~0ULL,k13=~0ULL,k14=~0ULL,k15=~0ULL;

// ---------------------------------------------------------------------------
// kNN pass 1: thread = (target i, chunk ch). 16 smallest d2 VALUES (u32).
// ---------------------------------------------------------------------------
__global__ __launch_bounds__(256) void knn_d2p1(const float4* __restrict__ pos4,
                                                unsigned* __restrict__ v) {
  __shared__ float4 cand[CH];
  int ch = blockIdx.x & (NCH - 1);
  int i  = (blockIdx.x >> 5) * 256 + threadIdx.x;
  cand[threadIdx.x] = pos4[ch * CH + threadIdx.x];
  __syncthreads();

  float4 p = pos4[i];
  U32INIT
  for (int jj = 0; jj < CH; ++jj) {
    unsigned key = d2key(p, cand[jj]);
    U32CHAIN(key)
  }
  unsigned* dst = v + (size_t)ch * 16 * NPTS + i;
  dst[0*(size_t)NPTS]=b0;   dst[1*(size_t)NPTS]=b1;   dst[2*(size_t)NPTS]=b2;
  dst[3*(size_t)NPTS]=b3;   dst[4*(size_t)NPTS]=b4;   dst[5*(size_t)NPTS]=b5;
  dst[6*(size_t)NPTS]=b6;   dst[7*(size_t)NPTS]=b7;   dst[8*(size_t)NPTS]=b8;
  dst[9*(size_t)NPTS]=b9;   dst[10*(size_t)NPTS]=b10; dst[11*(size_t)NPTS]=b11;
  dst[12*(size_t)NPTS]=b12; dst[13*(size_t)NPTS]=b13; dst[14*(size_t)NPTS]=b14;
  dst[15*(size_t)NPTS]=b15;
}

// ---------------------------------------------------------------------------
// kNN merge: merge 32 sorted 16-lists -> exact global 16th-smallest T[i].
// ---------------------------------------------------------------------------
__global__ __launch_bounds__(256) void knn_merge(const unsigned* __restrict__ v,
                                                 unsigned* __restrict__ T,
                                                 unsigned* __restrict__ cnt) {
  int i = blockIdx.x * 256 + threadIdx.x;
  U32INIT
  for (int ch = 0; ch < NCH; ++ch) {
    const unsigned* src = v + (size_t)ch * 16 * NPTS + i;
#pragma unroll 1
    for (int s = 0; s < 16; ++s) {
      unsigned key = src[(size_t)s * NPTS];
      if (key >= b15) break;
      U32CHAIN(key)
    }
  }
  T[i] = b15;
  cnt[i] = 0;
}

// ---------------------------------------------------------------------------
// kNN pass 2: re-scan (identical d2key bits); collect qualifiers (d2 <= T).
// ---------------------------------------------------------------------------
__global__ __launch_bounds__(256) void knn_d2p2(const float4* __restrict__ pos4,
                                                const unsigned* __restrict__ T,
                                                unsigned* __restrict__ cnt,
                                                u64* __restrict__ cbuf) {
  __shared__ float4 cand[CH];
  int ch = blockIdx.x & (NCH - 1);
  int i  = (blockIdx.x >> 5) * 256 + threadIdx.x;
  cand[threadIdx.x] = pos4[ch * CH + threadIdx.x];
  __syncthreads();

  float4 p = pos4[i];
  unsigned Ti = T[i];
  int jb = ch * CH;
  for (int jj = 0; jj < CH; ++jj) {
    unsigned key = d2key(p, cand[jj]);
    if (key <= Ti) {
      unsigned slot = atomicAdd(&cnt[i], 1u);
      if (slot < CAP)
        cbuf[(size_t)i * CAP + slot] = ((u64)key << 32) | (unsigned)(jb + jj);
    }
  }
}

// ---------------------------------------------------------------------------
// kNN select: exact lexicographic (d2, idx) top-16 over the <=CAP qualifiers.
// ---------------------------------------------------------------------------
__global__ __launch_bounds__(256) void knn_select(const unsigned* __restrict__ cnt,
                                                  const u64* __restrict__ cbuf,
                                                  int* __restrict__ idx_out) {
  int i = blockIdx.x * 256 + threadIdx.x;
  int c = (int)min(cnt[i], (unsigned)CAP);
  KINIT
#pragma unroll 1
  for (int q = 0; q < c; ++q) {
    u64 key = cbuf[(size_t)i * CAP + q];
    if (key < k15) { KCHAIN }
  }
  int* o = idx_out + i * 16;
  o[0]=(int)(unsigned)k0;   o[1]=(int)(unsigned)k1;   o[2]=(int)(unsigned)k2;
  o[3]=(int)(unsigned)k3;   o[4]=(int)(unsigned)k4;   o[5]=(int)(unsigned)k5;
  o[6]=(int)(unsigned)k6;   o[7]=(int)(unsigned)k7;   o[8]=(int)(unsigned)k8;
  o[9]=(int)(unsigned)k9;   o[10]=(int)(unsigned)k10; o[11]=(int)(unsigned)k11;
  o[12]=(int)(unsigned)k12; o[13]=(int)(unsigned)k13; o[14]=(int)(unsigned)k14;
  o[15]=(int)(unsigned)k15;
}

// ---------------------------------------------------------------------------
// conv1 TU: TU1[i][c] = b1[c] + pos[i] . (W1h[:,c] + W1p[:,c])   (K=3)
// ---------------------------------------------------------------------------
__global__ __launch_bounds__(256) void tu1_prep(const float* __restrict__ pos,
                                                const float* __restrict__ W1,
                                                const float* __restrict__ b1,
                                                float* __restrict__ TU) {
  int c = threadIdx.x;
  float w0 = W1[c]       + W1[768 + c];
  float w1 = W1[256 + c] + W1[1024 + c];
  float w2 = W1[512 + c] + W1[1280 + c];
  float bv = b1[c];
#pragma unroll
  for (int r = 0; r < 4; ++r) {
    int i = blockIdx.x * 4 + r;
    float x = pos[3 * i], y = pos[3 * i + 1], z = pos[3 * i + 2];
    TU[(size_t)i * 256 + c] = fmaf(x, w0, fmaf(y, w1, fmaf(z, w2, bv)));
  }
}

// ---------------------------------------------------------------------------
// MFMA GEMM: out[M][NCOLS] = act(bf16(A[M][KDIM]) @ Wf + bias [+ pos@W1p]).
// Block: 256 thr (4 waves), 32 rows; wave covers NF=NCOLS/64 16-col frags.
// A staged bf16 in XOR-swizzled LDS; B frag-major from global (L2-resident).
// ---------------------------------------------------------------------------
template <int NCOLS, int KDIM, int ACT, int ADDP>
__global__ __launch_bounds__(256) void gemm_mfma(
    const float* __restrict__ A,
    const short* __restrict__ wf,
    const float* __restrict__ bias,
    const float* __restrict__ pos,
    const float* __restrict__ W1p,
    float* __restrict__ out) {
  constexpr int KS = KDIM / 32;
  constexpr int NF = NCOLS / 64;
  __shared__ __align__(16) short As[32 * KDIM];

  int tid = threadIdx.x;
  int row0 = blockIdx.x * 32;

  {  // stage A: 32 rows x KDIM fp32 -> bf16, swizzled
    int row = tid & 31, wq = tid >> 5;
    const float* Ar = A + (size_t)(row0 + row) * KDIM;
#pragma unroll
    for (int q = 0; q < KDIM / 64; ++q) {
      int c0 = wq * 8 + q * 64;
      float4 a = *reinterpret_cast<const float4*>(Ar + c0);
      float4 b = *reinterpret_cast<const float4*>(Ar + c0 + 4);
      bf16x8 o;
      o[0] = f2bf(a.x); o[1] = f2bf(a.y); o[2] = f2bf(a.z); o[3] = f2bf(a.w);
      o[4] = f2bf(b.x); o[5] = f2bf(b.y); o[6] = f2bf(b.z); o[7] = f2bf(b.w);
      int byte = row * (KDIM * 2) + c0 * 2;
      byte ^= (row & 7) << 4;
      *reinterpret_cast<bf16x8*>(reinterpret_cast<char*>(As) + byte) = o;
    }
  }
  __syncthreads();

  int l = tid & 63, w = tid >> 6;
  int lhi = l >> 4, llo = l & 15;
  f32x4 zero = {0.f, 0.f, 0.f, 0.f};
  f32x4 acc[2][NF];
#pragma unroll
  for (int m = 0; m < 2; ++m)
#pragma unroll
    for (int n = 0; n < NF; ++n) acc[m][n] = zero;

  const bf16x8* WfV = reinterpret_cast<const bf16x8*>(wf);
#pragma unroll
  for (int ks = 0; ks < KS; ++ks) {
    bf16x8 af[2], bfr[NF];
#pragma unroll
    for (int m = 0; m < 2; ++m) {
      int r = m * 16 + llo;
      int byte = r * (KDIM * 2) + ks * 64 + lhi * 16;
      byte ^= (r & 7) << 4;
      af[m] = *reinterpret_cast<const bf16x8*>(
          reinterpret_cast<const char*>(As) + byte);
    }
#pragma unroll
    for (int n = 0; n < NF; ++n)
      bfr[n] = WfV[((w * NF + n) * KS + ks) * 64 + l];
#pragma unroll
    for (int m = 0; m < 2; ++m)
#pragma unroll
      for (int n = 0; n < NF; ++n)
        acc[m][n] = __builtin_amdgcn_mfma_f32_16x16x32_bf16(af[m], bfr[n],
                                                            acc[m][n], 0, 0, 0);
  }

  int cc[NF];
  float bv[NF], u0[NF], u1[NF], u2[NF];
#pragma unroll
  for (int n = 0; n < NF; ++n) {
    cc[n] = (w * NF + n) * 16 + llo;
    bv[n] = bias[cc[n]];
    if constexpr (ADDP) {
      u0[n] = W1p[cc[n]];
      u1[n] = W1p[NCOLS + cc[n]];
      u2[n] = W1p[2 * NCOLS + cc[n]];
    } else { u0[n] = u1[n] = u2[n] = 0.f; }
  }
#pragma unroll
  for (int m = 0; m < 2; ++m)
#pragma unroll
    for (int j = 0; j < 4; ++j) {
      int r = row0 + m * 16 + lhi * 4 + j;
      float px = 0.f, py = 0.f, pz = 0.f;
      if constexpr (ADDP) { px = pos[3*r]; py = pos[3*r+1]; pz = pos[3*r+2]; }
#pragma unroll
      for (int n = 0; n < NF; ++n) {
        float v = acc[m][n][j] + bv[n];
        if constexpr (ADDP) v += px * u0[n] + py * u1[n] + pz * u2[n];
        if (ACT == 1) v = fmaxf(v, 0.0f);
        out[(size_t)r * NCOLS + cc[n]] = v;
      }
    }
}

// ---------------------------------------------------------------------------
// MFMA conv: block = 4 targets (64 rows = 4 x 16 nbrs) x 256 cols, K=256.
// m1 = relu(TU[j] - U[i]) staged bf16 in XOR-swizzled LDS; B frag-major.
// Epilogue: max over 16 nbr-rows (in-frag + shfl), +b2, relu.
// ---------------------------------------------------------------------------
__global__ __launch_bounds__(256) void conv_mfma(
    const float* __restrict__ TU,
    const float* __restrict__ pos,
    const int* __restrict__ idx,
    const float* __restrict__ W1p,
    const short* __restrict__ w2f,
    const float* __restrict__ b2,
    float* __restrict__ hout) {
  __shared__ __align__(16) short m1s[64 * 256];
  __shared__ float Ub[4][256];
  __shared__ int js[64];

  int tid = threadIdx.x;
  int t0 = blockIdx.x * 4;
  if (tid < 64) js[tid] = idx[(t0 + (tid >> 4)) * 16 + (tid & 15)];
#pragma unroll
  for (int q = 0; q < 4; ++q) {
    int e = tid + 256 * q;
    int tg = e >> 8, c = e & 255;
    float x = pos[3 * (t0 + tg)], y = pos[3 * (t0 + tg) + 1],
          z = pos[3 * (t0 + tg) + 2];
    Ub[tg][c] = x * W1p[c] + y * W1p[256 + c] + z * W1p[512 + c];
  }
  __syncthreads();

  {
    int row = tid & 63;
    int wq = tid >> 6;
    int jrow = js[row];
    const float* TUj = TU + (size_t)jrow * 256;
    const float* Ui = &Ub[row >> 4][0];
#pragma unroll
    for (int q = 0; q < 8; ++q) {
      int c0 = wq * 8 + q * 32;
      float4 a = *reinterpret_cast<const float4*>(TUj + c0);
      float4 b = *reinterpret_cast<const float4*>(TUj + c0 + 4);
      float4 ua = *reinterpret_cast<const float4*>(Ui + c0);
      float4 ub = *reinterpret_cast<const float4*>(Ui + c0 + 4);
      bf16x8 o;
      o[0] = f2bf(fmaxf(a.x - ua.x, 0.f));
      o[1] = f2bf(fmaxf(a.y - ua.y, 0.f));
      o[2] = f2bf(fmaxf(a.z - ua.z, 0.f));
      o[3] = f2bf(fmaxf(a.w - ua.w, 0.f));
      o[4] = f2bf(fmaxf(b.x - ub.x, 0.f));
      o[5] = f2bf(fmaxf(b.y - ub.y, 0.f));
      o[6] = f2bf(fmaxf(b.z - ub.z, 0.f));
      o[7] = f2bf(fmaxf(b.w - ub.w, 0.f));
      int byte = row * 512 + c0 * 2;
      byte ^= (row & 7) << 4;
      *reinterpret_cast<bf16x8*>(reinterpret_cast<char*>(m1s) + byte) = o;
    }
  }
  __syncthreads();

  int l = tid & 63, w = tid >> 6;
  int lhi = l >> 4, llo = l & 15;
  f32x4 zero = {0.f, 0.f, 0.f, 0.f};
  f32x4 acc[4][4];
#pragma unroll
  for (int m = 0; m < 4; ++m)
#pragma unroll
    for (int n = 0; n < 4; ++n) acc[m][n] = zero;

  const bf16x8* Wf = reinterpret_cast<const bf16x8*>(w2f);
#pragma unroll
  for (int ks = 0; ks < 8; ++ks) {
    int k0 = ks * 32;
    bf16x8 af[4], bfr[4];
#pragma unroll
    for (int m = 0; m < 4; ++m) {
      int r = m * 16 + llo;
      int byte = r * 512 + k0 * 2 + lhi * 16;
      byte ^= (r & 7) << 4;
      af[m] = *reinterpret_cast<const bf16x8*>(
          reinterpret_cast<const char*>(m1s) + byte);
    }
#pragma unroll
    for (int n = 0; n < 4; ++n)
      bfr[n] = Wf[((w * 4 + n) * 8 + ks) * 64 + l];
#pragma unroll
    for (int m = 0; m < 4; ++m)
#pragma unroll
      for (int n = 0; n < 4; ++n)
        acc[m][n] = __builtin_amdgcn_mfma_f32_16x16x32_bf16(af[m], bfr[n],
                                                            acc[m][n], 0, 0, 0);
  }

#pragma unroll
  for (int m = 0; m < 4; ++m)
#pragma unroll
    for (int n = 0; n < 4; ++n) {
      float v = fmaxf(fmaxf(acc[m][n][0], acc[m][n][1]),
                      fmaxf(acc[m][n][2], acc[m][n][3]));
      v = fmaxf(v, __shfl_xor(v, 16));
      v = fmaxf(v, __shfl_xor(v, 32));
      if (lhi == 0) {
        int c = w * 64 + n * 16 + llo;
        hout[(size_t)(t0 + m) * CDIM + c] = fmaxf(v + b2[c], 0.0f);
      }
    }
}

// ---------------------------------------------------------------------------
// Final layer: out[r] = sigmoid(h2[r] . w3 + b3); one wave per row.
// ---------------------------------------------------------------------------
__global__ __launch_bounds__(64) void final_k(const float* __restrict__ h2,
                                              const float* __restrict__ w3,
                                              const float* __restrict__ b3,
                                              float* __restrict__ out) {
  int r = blockIdx.x, l = threadIdx.x;
  float s = h2[(size_t)r * HDIM + l] * w3[l] +
            h2[(size_t)r * HDIM + 64 + l] * w3[64 + l];
#pragma unroll
  for (int o = 32; o > 0; o >>= 1) s += __shfl_down(s, o);
  if (l == 0) out[r] = 1.0f / (1.0f + expf(-(s + b3[0])));
}

extern "C" void kernel_launch(void* const* d_in, const int* in_sizes, int n_in,
                              void* d_out, int out_size, void* d_ws,
                              size_t ws_size, hipStream_t stream) {
  const float* pos   = (const float*)d_in[0];
  const float* c1_W1 = (const float*)d_in[1];
  const float* c1_b1 = (const float*)d_in[2];
  const float* c1_W2 = (const float*)d_in[3];
  const float* c1_b2 = (const float*)d_in[4];
  const float* c2_W1 = (const float*)d_in[5];
  const float* c2_b1 = (const float*)d_in[6];
  const float* c2_W2 = (const float*)d_in[7];
  const float* c2_b2 = (const float*)d_in[8];
  const float* c3_W1 = (const float*)d_in[9];
  const float* c3_b1 = (const float*)d_in[10];
  const float* c3_W2 = (const float*)d_in[11];
  const float* c3_b2 = (const float*)d_in[12];
  const float* h_W1  = (const float*)d_in[13];
  const float* h_b1  = (const float*)d_in[14];
  const float* h_W2  = (const float*)d_in[15];
  const float* h_b2  = (const float*)d_in[16];
  const float* h_W3  = (const float*)d_in[17];
  const float* h_b3  = (const float*)d_in[18];
  float* out = (float*)d_out;

  char* w = (char*)d_ws;
  const size_t MB = 1 << 20;
  const size_t KB = 1 << 10;
  int*      p_idx  = (int*)w;                           // 512K
  float4*   p_pos4 = (float4*)(w + 512 * KB);           // 128K
  unsigned* p_T    = (unsigned*)(w + 640 * KB);         // 32K
  unsigned* p_cnt  = (unsigned*)(w + 672 * KB);         // 32K
  short*    p_w2f1 = (short*)(w + 704 * KB);            // 128K
  short*    p_w2f2 = (short*)(w + 832 * KB);            // 128K
  short*    p_w2f3 = (short*)(w + 960 * KB);            // 128K
  short*    p_wc2a = (short*)(w + 1088 * KB);           // 128K
  short*    p_wc3a = (short*)(w + 1216 * KB);           // 128K
  short*    p_whW1 = (short*)(w + 1344 * KB);           // 64K
  short*    p_whW2 = (short*)(w + 1408 * KB);           // 32K
  u64*      p_cbuf = (u64*)(w + 1536 * KB);             // 3MB -> 4.5MB
  unsigned* p_v    = (unsigned*)(w + 5 * MB);           // 16MB [5,21) knn only
  float*    p_TU   = (float*)(w + 5 * MB);              // 8MB (after knn)
  float*    p_hA   = (float*)(w + 13 * MB);             // 8MB
  float*    p_hB   = (float*)(w + 21 * MB);             // 8MB
  float*    p_c1   = (float*)(w + 5 * MB);              // 4MB (after conv3)
  float*    p_c2   = (float*)(w + 9 * MB);              // 4MB

  // kNN: two-pass exact top-16
  pos4_prep<<<NPTS / 256, 256, 0, stream>>>(pos, p_pos4);
  knn_d2p1<<<(NPTS / 256) * NCH, 256, 0, stream>>>(p_pos4, p_v);
  knn_merge<<<NPTS / 256, 256, 0, stream>>>(p_v, p_T, p_cnt);
  knn_d2p2<<<(NPTS / 256) * NCH, 256, 0, stream>>>(p_pos4, p_T, p_cnt, p_cbuf);
  knn_select<<<NPTS / 256, 256, 0, stream>>>(p_cnt, p_cbuf, p_idx);

  // weight preps (fragment-major bf16)
  wf_prep<256, 256><<<256, 256, 0, stream>>>(c1_W2, p_w2f1);
  wf_prep<256, 256><<<256, 256, 0, stream>>>(c2_W2, p_w2f2);
  wf_prep<256, 256><<<256, 256, 0, stream>>>(c3_W2, p_w2f3);
  wf_prep<256, 256><<<256, 256, 0, stream>>>(c2_W1, p_wc2a);
  wf_prep<256, 256><<<256, 256, 0, stream>>>(c3_W1, p_wc3a);
  wf_prep<256, 128><<<128, 256, 0, stream>>>(h_W1, p_whW1);
  wf_prep<128, 128><<<64, 256, 0, stream>>>(h_W2, p_whW2);

  // conv1 (h = pos, K=3): trivial TU build
  tu1_prep<<<NPTS / 4, 256, 0, stream>>>(pos, c1_W1, c1_b1, p_TU);
  conv_mfma<<<NPTS / 4, 256, 0, stream>>>(p_TU, pos, p_idx, c1_W1 + 3 * 256,
                                          p_w2f1, c1_b2, p_hA);
  // conv2
  gemm_mfma<256, 256, 0, 1><<<NPTS / 32, 256, 0, stream>>>(
      p_hA, p_wc2a, c2_b1, pos, c2_W1 + 256 * 256, p_TU);
  conv_mfma<<<NPTS / 4, 256, 0, stream>>>(p_TU, pos, p_idx, c2_W1 + 256 * 256,
                                          p_w2f2, c2_b2, p_hB);
  // conv3
  gemm_mfma<256, 256, 0, 1><<<NPTS / 32, 256, 0, stream>>>(
      p_hB, p_wc3a, c3_b1, pos, c3_W1 + 256 * 256, p_TU);
  conv_mfma<<<NPTS / 4, 256, 0, stream>>>(p_TU, pos, p_idx, c3_W1 + 256 * 256,
                                          p_w2f3, c3_b2, p_hA);
  // classifier
  gemm_mfma<128, 256, 1, 0><<<NPTS / 32, 256, 0, stream>>>(
      p_hA, p_whW1, h_b1, nullptr, nullptr, p_c1);
  gemm_mfma<128, 128, 1, 0><<<NPTS / 32, 256, 0, stream>>>(
      p_c1, p_whW2, h_b2, nullptr, nullptr, p_c2);
  final_k<<<NPTS, 64, 0, stream>>>(p_c2, h_W3, h_b3, out);

  (void)in_sizes; (void)n_in; (void)out_size; (void)ws_size;
}

// Round 7
// 323.870 us; speedup vs baseline: 5.0594x; 1.1594x over previous
//
#include <hip/hip_runtime.h>
#include <hip/hip_bf16.h>
#include <math.h>

#define NPTS 8192
#define CDIM 256
#define HDIM 128
#define NCH  32
#define CH   (NPTS / NCH)     // 256 candidates per chunk
#define CAP  48               // qualifier buffer slots per target

typedef __attribute__((ext_vector_type(8))) short bf16x8;
typedef __attribute__((ext_vector_type(4))) float f32x4;
typedef unsigned long long u64;

static __device__ __forceinline__ short f2bf(float f) {
  __hip_bfloat16 h = __float2bfloat16(f);
  return *reinterpret_cast<short*>(&h);
}

// median-of-3: one VALU op; med3(lo, key, hi) == min(max(lo,key),hi) for lo<=hi
static __device__ __forceinline__ unsigned umed3(unsigned a, unsigned b,
                                                 unsigned c) {
  unsigned d;
  asm("v_med3_u32 %0, %1, %2, %3" : "=v"(d) : "v"(a), "v"(b), "v"(c));
  return d;
}

// Bit-exact d2 key shared by both kNN passes.
static __device__ __forceinline__ unsigned d2key(float4 p, float4 c) {
  float dot = fmaf(p.x, c.x, fmaf(p.y, c.y, p.z * c.z));
  float d2 = fmaf(-2.0f, dot, p.w + c.w);
  return __float_as_uint(fmaxf(d2, 0.0f));
}

// ---------------------------------------------------------------------------
// Prep: pos4[i] = (x, y, z, x^2+y^2+z^2)
// ---------------------------------------------------------------------------
__global__ __launch_bounds__(256) void pos4_prep(const float* __restrict__ pos,
                                                 float4* __restrict__ pos4) {
  int i = blockIdx.x * 256 + threadIdx.x;
  float x = pos[3 * i], y = pos[3 * i + 1], z = pos[3 * i + 2];
  pos4[i] = make_float4(x, y, z, x * x + y * y + z * z);
}

// ---------------------------------------------------------------------------
// Prep: fragment-major bf16 weights. Flat index t = (((c16*KS)+ks)*64+l)*8+q;
// element (k, c) = (ks*32 + (l>>4)*8 + q, c16*16 + (l&15)).
// ---------------------------------------------------------------------------
template <int KDIM, int NCOLS>
__global__ __launch_bounds__(256) void wf_prep(const float* __restrict__ W,
                                               short* __restrict__ wf) {
  int t = blockIdx.x * 256 + threadIdx.x;
  constexpr int KS = KDIM / 32;
  int q = t & 7, l = (t >> 3) & 63, F = t >> 9;
  int ks = F % KS, c16 = F / KS;
  int k = ks * 32 + ((l >> 4) << 3) + q;
  int c = c16 * 16 + (l & 15);
  wf[t] = f2bf(W[k * NCOLS + c]);
}

// u32 branchless top-16 insert: b[s] = med3(b[s-1], key, b[s]) (16 indep ops).
#define U32INIT unsigned b0=~0u,b1=~0u,b2=~0u,b3=~0u,b4=~0u,b5=~0u,b6=~0u, \
                         b7=~0u,b8=~0u,b9=~0u,b10=~0u,b11=~0u,b12=~0u, \
                         b13=~0u,b14=~0u,b15=~0u;
#define U32CHAIN(key) { \
  b15 = umed3(b14, key, b15); b14 = umed3(b13, key, b14); \
  b13 = umed3(b12, key, b13); b12 = umed3(b11, key, b12); \
  b11 = umed3(b10, key, b11); b10 = umed3(b9,  key, b10); \
  b9  = umed3(b8,  key, b9);  b8  = umed3(b7,  key, b8);  \
  b7  = umed3(b6,  key, b7);  b6  = umed3(b5,  key, b6);  \
  b5  = umed3(b4,  key, b5);  b4  = umed3(b3,  key, b4);  \
  b3  = umed3(b2,  key, b3);  b2  = umed3(b1,  key, b2);  \
  b1  = umed3(b0,  key, b1);  b0  = min(b0, key); }

// u64 exact (d2,idx) insertion chain for the final select.
#define KSTEP(s) { bool sw_ = key < k##s; u64 t_ = k##s; \
                   k##s = sw_ ? key : t_; key = sw_ ? t_ : key; }
#define KCHAIN KSTEP(0) KSTEP(1) KSTEP(2) KSTEP(3) KSTEP(4) KSTEP(5) \
               KSTEP(6) KSTEP(7) KSTEP(8) KSTEP(9) KSTEP(10) KSTEP(11) \
               KSTEP(12) KSTEP(13) KSTEP(14) KSTEP(15)
#define KINIT u64 k0=~0ULL,k1=~0ULL,k2=~0ULL,k3=~0ULL,k4=~0ULL,k5=~0ULL, \
                  k6=~0ULL,k7=~0ULL,k8=~0ULL,k9=~0ULL,k10=~0ULL,k11=~0ULL, \
                  k12=~0ULL,k13=~0ULL,k14=~0ULL,k15=~0ULL;

// ---------------------------------------------------------------------------
// kNN pass 1: thread = (target i, chunk ch). 16 smallest d2 VALUES (u32),
// written contiguously per (ch, i) for the wave-parallel merge.
// ---------------------------------------------------------------------------
__global__ __launch_bounds__(256) void knn_d2p1(const float4* __restrict__ pos4,
                                                unsigned* __restrict__ v) {
  __shared__ float4 cand[CH];
  int ch = blockIdx.x & (NCH - 1);
  int i  = (blockIdx.x >> 5) * 256 + threadIdx.x;
  cand[threadIdx.x] = pos4[ch * CH + threadIdx.x];
  __syncthreads();

  float4 p = pos4[i];
  U32INIT
  for (int jj = 0; jj < CH; ++jj) {
    unsigned key = d2key(p, cand[jj]);
    U32CHAIN(key)
  }
  uint4* dst = reinterpret_cast<uint4*>(v + ((size_t)ch * NPTS + i) * 16);
  dst[0] = make_uint4(b0, b1, b2, b3);
  dst[1] = make_uint4(b4, b5, b6, b7);
  dst[2] = make_uint4(b8, b9, b10, b11);
  dst[3] = make_uint4(b12, b13, b14, b15);
}

// ---------------------------------------------------------------------------
// kNN merge: one WAVE per target. Lane l holds 8 sorted values (half of chunk
// l>>1). 16 selection rounds: wave-min of lane heads, exactly one holder
// (lowest lane, tie-safe via ballot+ffs) advances. Last min = exact global
// 16th-smallest d2 -> T[i]. All loads issued upfront; high occupancy.
// ---------------------------------------------------------------------------
__global__ __launch_bounds__(256) void knn_merge(const unsigned* __restrict__ v,
                                                 unsigned* __restrict__ T,
                                                 unsigned* __restrict__ cnt) {
  int wv = threadIdx.x >> 6, lane = threadIdx.x & 63;
  int i = blockIdx.x * 4 + wv;
  int ch = lane >> 1, half = lane & 1;
  const uint4* src = reinterpret_cast<const uint4*>(
      v + ((size_t)ch * NPTS + i) * 16 + half * 8);
  uint4 a = src[0], b = src[1];
  unsigned r1 = a.y, r2 = a.z, r3 = a.w;
  unsigned r4 = b.x, r5 = b.y, r6 = b.z, r7 = b.w;
  unsigned h = a.x;
  int idx = 0;
  unsigned wmin = 0;
#pragma unroll
  for (int round = 0; round < 16; ++round) {
    unsigned m = h;
    m = min(m, (unsigned)__shfl_xor((int)m, 1));
    m = min(m, (unsigned)__shfl_xor((int)m, 2));
    m = min(m, (unsigned)__shfl_xor((int)m, 4));
    m = min(m, (unsigned)__shfl_xor((int)m, 8));
    m = min(m, (unsigned)__shfl_xor((int)m, 16));
    m = min(m, (unsigned)__shfl_xor((int)m, 32));
    wmin = m;
    u64 ball = __ballot(h == m);
    int src_lane = __ffsll(ball) - 1;
    if (lane == src_lane) {
      ++idx;
      h = idx == 1 ? r1 : idx == 2 ? r2 : idx == 3 ? r3 : idx == 4 ? r4 :
          idx == 5 ? r5 : idx == 6 ? r6 : idx == 7 ? r7 : 0xFFFFFFFFu;
    }
  }
  if (lane == 0) { T[i] = wmin; cnt[i] = 0; }
}

// ---------------------------------------------------------------------------
// kNN pass 2: re-scan (identical d2key bits); collect qualifiers (d2 <= T).
// ---------------------------------------------------------------------------
__global__ __launch_bounds__(256) void knn_d2p2(const float4* __restrict__ pos4,
                                                const unsigned* __restrict__ T,
                                                unsigned* __restrict__ cnt,
                                                u64* __restrict__ cbuf) {
  __shared__ float4 cand[CH];
  int ch = blockIdx.x & (NCH - 1);
  int i  = (blockIdx.x >> 5) * 256 + threadIdx.x;
  cand[threadIdx.x] = pos4[ch * CH + threadIdx.x];
  __syncthreads();

  float4 p = pos4[i];
  unsigned Ti = T[i];
  int jb = ch * CH;
  for (int jj = 0; jj < CH; ++jj) {
    unsigned key = d2key(p, cand[jj]);
    if (key <= Ti) {
      unsigned slot = atomicAdd(&cnt[i], 1u);
      if (slot < CAP)
        cbuf[(size_t)i * CAP + slot] = ((u64)key << 32) | (unsigned)(jb + jj);
    }
  }
}

// ---------------------------------------------------------------------------
// kNN select: exact lexicographic (d2, idx) top-16 over the <=CAP qualifiers.
// ---------------------------------------------------------------------------
__global__ __launch_bounds__(256) void knn_select(const unsigned* __restrict__ cnt,
                                                  const u64* __restrict__ cbuf,
                                                  int* __restrict__ idx_out) {
  int i = blockIdx.x * 256 + threadIdx.x;
  int c = (int)min(cnt[i], (unsigned)CAP);
  KINIT
#pragma unroll 1
  for (int q = 0; q < c; ++q) {
    u64 key = cbuf[(size_t)i * CAP + q];
    if (key < k15) { KCHAIN }
  }
  int* o = idx_out + i * 16;
  o[0]=(int)(unsigned)k0;   o[1]=(int)(unsigned)k1;   o[2]=(int)(unsigned)k2;
  o[3]=(int)(unsigned)k3;   o[4]=(int)(unsigned)k4;   o[5]=(int)(unsigned)k5;
  o[6]=(int)(unsigned)k6;   o[7]=(int)(unsigned)k7;   o[8]=(int)(unsigned)k8;
  o[9]=(int)(unsigned)k9;   o[10]=(int)(unsigned)k10; o[11]=(int)(unsigned)k11;
  o[12]=(int)(unsigned)k12; o[13]=(int)(unsigned)k13; o[14]=(int)(unsigned)k14;
  o[15]=(int)(unsigned)k15;
}

// ---------------------------------------------------------------------------
// conv1 TU: TU1[i][c] = b1[c] + pos[i] . (W1h[:,c] + W1p[:,c])   (K=3)
// ---------------------------------------------------------------------------
__global__ __launch_bounds__(256) void tu1_prep(const float* __restrict__ pos,
                                                const float* __restrict__ W1,
                                                const float* __restrict__ b1,
                                                float* __restrict__ TU) {
  int c = threadIdx.x;
  float w0 = W1[c]       + W1[768 + c];
  float w1 = W1[256 + c] + W1[1024 + c];
  float w2 = W1[512 + c] + W1[1280 + c];
  float bv = b1[c];
#pragma unroll
  for (int r = 0; r < 4; ++r) {
    int i = blockIdx.x * 4 + r;
    float x = pos[3 * i], y = pos[3 * i + 1], z = pos[3 * i + 2];
    TU[(size_t)i * 256 + c] = fmaf(x, w0, fmaf(y, w1, fmaf(z, w2, bv)));
  }
}

// ---------------------------------------------------------------------------
// MFMA GEMM: out[M][NCOLS] = act(bf16(A[M][KDIM]) @ Wf + bias [+ pos@W1p]).
// ---------------------------------------------------------------------------
template <int NCOLS, int KDIM, int ACT, int ADDP>
__global__ __launch_bounds__(256) void gemm_mfma(
    const float* __restrict__ A,
    const short* __restrict__ wf,
    const float* __restrict__ bias,
    const float* __restrict__ pos,
    const float* __restrict__ W1p,
    float* __restrict__ out) {
  constexpr int KS = KDIM / 32;
  constexpr int NF = NCOLS / 64;
  __shared__ __align__(16) short As[32 * KDIM];

  int tid = threadIdx.x;
  int row0 = blockIdx.x * 32;

  {  // stage A: 32 rows x KDIM fp32 -> bf16, swizzled
    int row = tid & 31, wq = tid >> 5;
    const float* Ar = A + (size_t)(row0 + row) * KDIM;
#pragma unroll
    for (int q = 0; q < KDIM / 64; ++q) {
      int c0 = wq * 8 + q * 64;
      float4 a = *reinterpret_cast<const float4*>(Ar + c0);
      float4 b = *reinterpret_cast<const float4*>(Ar + c0 + 4);
      bf16x8 o;
      o[0] = f2bf(a.x); o[1] = f2bf(a.y); o[2] = f2bf(a.z); o[3] = f2bf(a.w);
      o[4] = f2bf(b.x); o[5] = f2bf(b.y); o[6] = f2bf(b.z); o[7] = f2bf(b.w);
      int byte = row * (KDIM * 2) + c0 * 2;
      byte ^= (row & 7) << 4;
      *reinterpret_cast<bf16x8*>(reinterpret_cast<char*>(As) + byte) = o;
    }
  }
  __syncthreads();

  int l = tid & 63, w = tid >> 6;
  int lhi = l >> 4, llo = l & 15;
  f32x4 zero = {0.f, 0.f, 0.f, 0.f};
  f32x4 acc[2][NF];
#pragma unroll
  for (int m = 0; m < 2; ++m)
#pragma unroll
    for (int n = 0; n < NF; ++n) acc[m][n] = zero;

  const bf16x8* WfV = reinterpret_cast<const bf16x8*>(wf);
#pragma unroll
  for (int ks = 0; ks < KS; ++ks) {
    bf16x8 af[2], bfr[NF];
#pragma unroll
    for (int m = 0; m < 2; ++m) {
      int r = m * 16 + llo;
      int byte = r * (KDIM * 2) + ks * 64 + lhi * 16;
      byte ^= (r & 7) << 4;
      af[m] = *reinterpret_cast<const bf16x8*>(
          reinterpret_cast<const char*>(As) + byte);
    }
#pragma unroll
    for (int n = 0; n < NF; ++n)
      bfr[n] = WfV[((w * NF + n) * KS + ks) * 64 + l];
#pragma unroll
    for (int m = 0; m < 2; ++m)
#pragma unroll
      for (int n = 0; n < NF; ++n)
        acc[m][n] = __builtin_amdgcn_mfma_f32_16x16x32_bf16(af[m], bfr[n],
                                                            acc[m][n], 0, 0, 0);
  }

  int cc[NF];
  float bv[NF], u0[NF], u1[NF], u2[NF];
#pragma unroll
  for (int n = 0; n < NF; ++n) {
    cc[n] = (w * NF + n) * 16 + llo;
    bv[n] = bias[cc[n]];
    if constexpr (ADDP) {
      u0[n] = W1p[cc[n]];
      u1[n] = W1p[NCOLS + cc[n]];
      u2[n] = W1p[2 * NCOLS + cc[n]];
    } else { u0[n] = u1[n] = u2[n] = 0.f; }
  }
#pragma unroll
  for (int m = 0; m < 2; ++m)
#pragma unroll
    for (int j = 0; j < 4; ++j) {
      int r = row0 + m * 16 + lhi * 4 + j;
      float px = 0.f, py = 0.f, pz = 0.f;
      if constexpr (ADDP) { px = pos[3*r]; py = pos[3*r+1]; pz = pos[3*r+2]; }
#pragma unroll
      for (int n = 0; n < NF; ++n) {
        float v = acc[m][n][j] + bv[n];
        if constexpr (ADDP) v += px * u0[n] + py * u1[n] + pz * u2[n];
        if (ACT == 1) v = fmaxf(v, 0.0f);
        out[(size_t)r * NCOLS + cc[n]] = v;
      }
    }
}

// ---------------------------------------------------------------------------
// MFMA conv: block = 4 targets (64 rows = 4 x 16 nbrs) x 256 cols, K=256.
// ---------------------------------------------------------------------------
__global__ __launch_bounds__(256) void conv_mfma(
    const float* __restrict__ TU,
    const float* __restrict__ pos,
    const int* __restrict__ idx,
    const float* __restrict__ W1p,
    const short* __restrict__ w2f,
    const float* __restrict__ b2,
    float* __restrict__ hout) {
  __shared__ __align__(16) short m1s[64 * 256];
  __shared__ float Ub[4][256];
  __shared__ int js[64];

  int tid = threadIdx.x;
  int t0 = blockIdx.x * 4;
  if (tid < 64) js[tid] = idx[(t0 + (tid >> 4)) * 16 + (tid & 15)];
#pragma unroll
  for (int q = 0; q < 4; ++q) {
    int e = tid + 256 * q;
    int tg = e >> 8, c = e & 255;
    float x = pos[3 * (t0 + tg)], y = pos[3 * (t0 + tg) + 1],
          z = pos[3 * (t0 + tg) + 2];
    Ub[tg][c] = x * W1p[c] + y * W1p[256 + c] + z * W1p[512 + c];
  }
  __syncthreads();

  {
    int row = tid & 63;
    int wq = tid >> 6;
    int jrow = js[row];
    const float* TUj = TU + (size_t)jrow * 256;
    const float* Ui = &Ub[row >> 4][0];
#pragma unroll
    for (int q = 0; q < 8; ++q) {
      int c0 = wq * 8 + q * 32;
      float4 a = *reinterpret_cast<const float4*>(TUj + c0);
      float4 b = *reinterpret_cast<const float4*>(TUj + c0 + 4);
      float4 ua = *reinterpret_cast<const float4*>(Ui + c0);
      float4 ub = *reinterpret_cast<const float4*>(Ui + c0 + 4);
      bf16x8 o;
      o[0] = f2bf(fmaxf(a.x - ua.x, 0.f));
      o[1] = f2bf(fmaxf(a.y - ua.y, 0.f));
      o[2] = f2bf(fmaxf(a.z - ua.z, 0.f));
      o[3] = f2bf(fmaxf(a.w - ua.w, 0.f));
      o[4] = f2bf(fmaxf(b.x - ub.x, 0.f));
      o[5] = f2bf(fmaxf(b.y - ub.y, 0.f));
      o[6] = f2bf(fmaxf(b.z - ub.z, 0.f));
      o[7] = f2bf(fmaxf(b.w - ub.w, 0.f));
      int byte = row * 512 + c0 * 2;
      byte ^= (row & 7) << 4;
      *reinterpret_cast<bf16x8*>(reinterpret_cast<char*>(m1s) + byte) = o;
    }
  }
  __syncthreads();

  int l = tid & 63, w = tid >> 6;
  int lhi = l >> 4, llo = l & 15;
  f32x4 zero = {0.f, 0.f, 0.f, 0.f};
  f32x4 acc[4][4];
#pragma unroll
  for (int m = 0; m < 4; ++m)
#pragma unroll
    for (int n = 0; n < 4; ++n) acc[m][n] = zero;

  const bf16x8* Wf = reinterpret_cast<const bf16x8*>(w2f);
#pragma unroll
  for (int ks = 0; ks < 8; ++ks) {
    int k0 = ks * 32;
    bf16x8 af[4], bfr[4];
#pragma unroll
    for (int m = 0; m < 4; ++m) {
      int r = m * 16 + llo;
      int byte = r * 512 + k0 * 2 + lhi * 16;
      byte ^= (r & 7) << 4;
      af[m] = *reinterpret_cast<const bf16x8*>(
          reinterpret_cast<const char*>(m1s) + byte);
    }
#pragma unroll
    for (int n = 0; n < 4; ++n)
      bfr[n] = Wf[((w * 4 + n) * 8 + ks) * 64 + l];
#pragma unroll
    for (int m = 0; m < 4; ++m)
#pragma unroll
      for (int n = 0; n < 4; ++n)
        acc[m][n] = __builtin_amdgcn_mfma_f32_16x16x32_bf16(af[m], bfr[n],
                                                            acc[m][n], 0, 0, 0);
  }

#pragma unroll
  for (int m = 0; m < 4; ++m)
#pragma unroll
    for (int n = 0; n < 4; ++n) {
      float v = fmaxf(fmaxf(acc[m][n][0], acc[m][n][1]),
                      fmaxf(acc[m][n][2], acc[m][n][3]));
      v = fmaxf(v, __shfl_xor(v, 16));
      v = fmaxf(v, __shfl_xor(v, 32));
      if (lhi == 0) {
        int c = w * 64 + n * 16 + llo;
        hout[(size_t)(t0 + m) * CDIM + c] = fmaxf(v + b2[c], 0.0f);
      }
    }
}

// ---------------------------------------------------------------------------
// Final layer: out[r] = sigmoid(h2[r] . w3 + b3); one wave per row.
// ---------------------------------------------------------------------------
__global__ __launch_bounds__(64) void final_k(const float* __restrict__ h2,
                                              const float* __restrict__ w3,
                                              const float* __restrict__ b3,
                                              float* __restrict__ out) {
  int r = blockIdx.x, l = threadIdx.x;
  float s = h2[(size_t)r * HDIM + l] * w3[l] +
            h2[(size_t)r * HDIM + 64 + l] * w3[64 + l];
#pragma unroll
  for (int o = 32; o > 0; o >>= 1) s += __shfl_down(s, o);
  if (l == 0) out[r] = 1.0f / (1.0f + expf(-(s + b3[0])));
}

extern "C" void kernel_launch(void* const* d_in, const int* in_sizes, int n_in,
                              void* d_out, int out_size, void* d_ws,
                              size_t ws_size, hipStream_t stream) {
  const float* pos   = (const float*)d_in[0];
  const float* c1_W1 = (const float*)d_in[1];
  const float* c1_b1 = (const float*)d_in[2];
  const float* c1_W2 = (const float*)d_in[3];
  const float* c1_b2 = (const float*)d_in[4];
  const float* c2_W1 = (const float*)d_in[5];
  const float* c2_b1 = (const float*)d_in[6];
  const float* c2_W2 = (const float*)d_in[7];
  const float* c2_b2 = (const float*)d_in[8];
  const float* c3_W1 = (const float*)d_in[9];
  const float* c3_b1 = (const float*)d_in[10];
  const float* c3_W2 = (const float*)d_in[11];
  const float* c3_b2 = (const float*)d_in[12];
  const float* h_W1  = (const float*)d_in[13];
  const float* h_b1  = (const float*)d_in[14];
  const float* h_W2  = (const float*)d_in[15];
  const float* h_b2  = (const float*)d_in[16];
  const float* h_W3  = (const float*)d_in[17];
  const float* h_b3  = (const float*)d_in[18];
  float* out = (float*)d_out;

  char* w = (char*)d_ws;
  const size_t MB = 1 << 20;
  const size_t KB = 1 << 10;
  int*      p_idx  = (int*)w;                           // 512K
  float4*   p_pos4 = (float4*)(w + 512 * KB);           // 128K
  unsigned* p_T    = (unsigned*)(w + 640 * KB);         // 32K
  unsigned* p_cnt  = (unsigned*)(w + 672 * KB);         // 32K
  short*    p_w2f1 = (short*)(w + 704 * KB);            // 128K
  short*    p_w2f2 = (short*)(w + 832 * KB);            // 128K
  short*    p_w2f3 = (short*)(w + 960 * KB);            // 128K
  short*    p_wc2a = (short*)(w + 1088 * KB);           // 128K
  short*    p_wc3a = (short*)(w + 1216 * KB);           // 128K
  short*    p_whW1 = (short*)(w + 1344 * KB);           // 64K
  short*    p_whW2 = (short*)(w + 1408 * KB);           // 32K
  u64*      p_cbuf = (u64*)(w + 1536 * KB);             // 3MB
  unsigned* p_v    = (unsigned*)(w + 5 * MB);           // 16MB [5,21) knn only
  float*    p_TU   = (float*)(w + 5 * MB);              // 8MB (after knn)
  float*    p_hA   = (float*)(w + 13 * MB);             // 8MB
  float*    p_hB   = (float*)(w + 21 * MB);             // 8MB
  float*    p_c1   = (float*)(w + 5 * MB);              // 4MB (after conv3)
  float*    p_c2   = (float*)(w + 9 * MB);              // 4MB

  // kNN: two-pass exact top-16 (wave-parallel merge)
  pos4_prep<<<NPTS / 256, 256, 0, stream>>>(pos, p_pos4);
  knn_d2p1<<<(NPTS / 256) * NCH, 256, 0, stream>>>(p_pos4, p_v);
  knn_merge<<<NPTS / 4, 256, 0, stream>>>(p_v, p_T, p_cnt);
  knn_d2p2<<<(NPTS / 256) * NCH, 256, 0, stream>>>(p_pos4, p_T, p_cnt, p_cbuf);
  knn_select<<<NPTS / 256, 256, 0, stream>>>(p_cnt, p_cbuf, p_idx);

  // weight preps (fragment-major bf16)
  wf_prep<256, 256><<<256, 256, 0, stream>>>(c1_W2, p_w2f1);
  wf_prep<256, 256><<<256, 256, 0, stream>>>(c2_W2, p_w2f2);
  wf_prep<256, 256><<<256, 256, 0, stream>>>(c3_W2, p_w2f3);
  wf_prep<256, 256><<<256, 256, 0, stream>>>(c2_W1, p_wc2a);
  wf_prep<256, 256><<<256, 256, 0, stream>>>(c3_W1, p_wc3a);
  wf_prep<256, 128><<<128, 256, 0, stream>>>(h_W1, p_whW1);
  wf_prep<128, 128><<<64, 256, 0, stream>>>(h_W2, p_whW2);

  // conv1 (h = pos, K=3): trivial TU build
  tu1_prep<<<NPTS / 4, 256, 0, stream>>>(pos, c1_W1, c1_b1, p_TU);
  conv_mfma<<<NPTS / 4, 256, 0, stream>>>(p_TU, pos, p_idx, c1_W1 + 3 * 256,
                                          p_w2f1, c1_b2, p_hA);
  // conv2
  gemm_mfma<256, 256, 0, 1><<<NPTS / 32, 256, 0, stream>>>(
      p_hA, p_wc2a, c2_b1, pos, c2_W1 + 256 * 256, p_TU);
  conv_mfma<<<NPTS / 4, 256, 0, stream>>>(p_TU, pos, p_idx, c2_W1 + 256 * 256,
                                          p_w2f2, c2_b2, p_hB);
  // conv3
  gemm_mfma<256, 256, 0, 1><<<NPTS / 32, 256, 0, stream>>>(
      p_hB, p_wc3a, c3_b1, pos, c3_W1 + 256 * 256, p_TU);
  conv_mfma<<<NPTS / 4, 256, 0, stream>>>(p_TU, pos, p_idx, c3_W1 + 256 * 256,
                                          p_w2f3, c3_b2, p_hA);
  // classifier
  gemm_mfma<128, 256, 1, 0><<<NPTS / 32, 256, 0, stream>>>(
      p_hA, p_whW1, h_b1, nullptr, nullptr, p_c1);
  gemm_mfma<128, 128, 1, 0><<<NPTS / 32, 256, 0, stream>>>(
      p_c1, p_whW2, h_b2, nullptr, nullptr, p_c2);
  final_k<<<NPTS, 64, 0, stream>>>(p_c2, h_W3, h_b3, out);

  (void)in_sizes; (void)n_in; (void)out_size; (void)ws_size;
}

// Round 8
// 289.729 us; speedup vs baseline: 5.6556x; 1.1178x over previous
//
#include <hip/hip_runtime.h>
#include <hip/hip_bf16.h>
#include <math.h>

#define NPTS 8192
#define CDIM 256
#define HDIM 128
#define NCH  32
#define CH   (NPTS / NCH)     // 256 candidates per chunk
#define CAP  48               // qualifier buffer slots per target

typedef __attribute__((ext_vector_type(8))) short bf16x8;
typedef __attribute__((ext_vector_type(4))) float f32x4;
typedef unsigned long long u64;

static __device__ __forceinline__ short f2bf(float f) {
  __hip_bfloat16 h = __float2bfloat16(f);
  return *reinterpret_cast<short*>(&h);
}

// median-of-3: one VALU op; med3(lo, key, hi) == min(max(lo,key),hi) for lo<=hi
static __device__ __forceinline__ unsigned umed3(unsigned a, unsigned b,
                                                 unsigned c) {
  unsigned d;
  asm("v_med3_u32 %0, %1, %2, %3" : "=v"(d) : "v"(a), "v"(b), "v"(c));
  return d;
}

// Bit-exact d2 key shared by both kNN passes.
static __device__ __forceinline__ unsigned d2key(float4 p, float4 c) {
  float dot = fmaf(p.x, c.x, fmaf(p.y, c.y, p.z * c.z));
  float d2 = fmaf(-2.0f, dot, p.w + c.w);
  return __float_as_uint(fmaxf(d2, 0.0f));
}

// u32 branchless top-16 insert: b[s] = med3(b[s-1], key, b[s]) (16 indep ops).
#define U32INIT unsigned b0=~0u,b1=~0u,b2=~0u,b3=~0u,b4=~0u,b5=~0u,b6=~0u, \
                         b7=~0u,b8=~0u,b9=~0u,b10=~0u,b11=~0u,b12=~0u, \
                         b13=~0u,b14=~0u,b15=~0u;
#define U32CHAIN(key) { \
  b15 = umed3(b14, key, b15); b14 = umed3(b13, key, b14); \
  b13 = umed3(b12, key, b13); b12 = umed3(b11, key, b12); \
  b11 = umed3(b10, key, b11); b10 = umed3(b9,  key, b10); \
  b9  = umed3(b8,  key, b9);  b8  = umed3(b7,  key, b8);  \
  b7  = umed3(b6,  key, b7);  b6  = umed3(b5,  key, b6);  \
  b5  = umed3(b4,  key, b5);  b4  = umed3(b3,  key, b4);  \
  b3  = umed3(b2,  key, b3);  b2  = umed3(b1,  key, b2);  \
  b1  = umed3(b0,  key, b1);  b0  = min(b0, key); }

// u64 exact (d2,idx) insertion chain for the final select.
#define KSTEP(s) { bool sw_ = key < k##s; u64 t_ = k##s; \
                   k##s = sw_ ? key : t_; key = sw_ ? t_ : key; }
#define KCHAIN KSTEP(0) KSTEP(1) KSTEP(2) KSTEP(3) KSTEP(4) KSTEP(5) \
               KSTEP(6) KSTEP(7) KSTEP(8) KSTEP(9) KSTEP(10) KSTEP(11) \
               KSTEP(12) KSTEP(13) KSTEP(14) KSTEP(15)
#define KINIT u64 k0=~0ULL,k1=~0ULL,k2=~0ULL,k3=~0ULL,k4=~0ULL,k5=~0ULL, \
                  k6=~0ULL,k7=~0ULL,k8=~0ULL,k9=~0ULL,k10=~0ULL,k11=~0ULL, \
                  k12=~0ULL,k13=~0ULL,k14=~0ULL,k15=~0ULL;

// ---------------------------------------------------------------------------
// Fused prep: 7 fragment-major bf16 weight conversions + pos4 + conv1 TU.
// blocks [0,1280): the five 256x256 weights; [1280,1408): h_W1 (256x128);
// [1408,1472): h_W2 (128x128); [1472,1504): pos4; [1504,2016): tu1 (16 rows).
// ---------------------------------------------------------------------------
__global__ __launch_bounds__(256) void prep_all(
    const float* __restrict__ c1W2, const float* __restrict__ c2W2,
    const float* __restrict__ c3W2, const float* __restrict__ c2W1,
    const float* __restrict__ c3W1, const float* __restrict__ hW1,
    const float* __restrict__ hW2,
    short* __restrict__ w2f1, short* __restrict__ w2f2,
    short* __restrict__ w2f3, short* __restrict__ wc2a,
    short* __restrict__ wc3a, short* __restrict__ whW1,
    short* __restrict__ whW2,
    const float* __restrict__ pos, float4* __restrict__ pos4,
    const float* __restrict__ c1W1, const float* __restrict__ c1b1,
    float* __restrict__ TU) {
  int b = blockIdx.x, tid = threadIdx.x;
  if (b < 1280) {                 // 256x256 weights, KS=8
    const float* W; short* wf; int rb;
    if (b < 256)       { W = c1W2; wf = w2f1; rb = b; }
    else if (b < 512)  { W = c2W2; wf = w2f2; rb = b - 256; }
    else if (b < 768)  { W = c3W2; wf = w2f3; rb = b - 512; }
    else if (b < 1024) { W = c2W1; wf = wc2a; rb = b - 768; }
    else               { W = c3W1; wf = wc3a; rb = b - 1024; }
    int t = rb * 256 + tid;
    int q = t & 7, l = (t >> 3) & 63, F = t >> 9;
    int ks = F & 7, c16 = F >> 3;
    int k = ks * 32 + ((l >> 4) << 3) + q;
    int c = c16 * 16 + (l & 15);
    wf[t] = f2bf(W[k * 256 + c]);
  } else if (b < 1408) {          // h_W1: KDIM 256 (KS=8), NCOLS 128
    int t = (b - 1280) * 256 + tid;
    int q = t & 7, l = (t >> 3) & 63, F = t >> 9;
    int ks = F & 7, c16 = F >> 3;
    int k = ks * 32 + ((l >> 4) << 3) + q;
    int c = c16 * 16 + (l & 15);
    whW1[t] = f2bf(hW1[k * 128 + c]);
  } else if (b < 1472) {          // h_W2: KDIM 128 (KS=4), NCOLS 128
    int t = (b - 1408) * 256 + tid;
    int q = t & 7, l = (t >> 3) & 63, F = t >> 9;
    int ks = F & 3, c16 = F >> 2;
    int k = ks * 32 + ((l >> 4) << 3) + q;
    int c = c16 * 16 + (l & 15);
    whW2[t] = f2bf(hW2[k * 128 + c]);
  } else if (b < 1504) {          // pos4
    int i = (b - 1472) * 256 + tid;
    float x = pos[3 * i], y = pos[3 * i + 1], z = pos[3 * i + 2];
    pos4[i] = make_float4(x, y, z, x * x + y * y + z * z);
  } else {                        // conv1 TU: TU[i][c] = b1 + pos.(W1h+W1p)
    int c = tid;
    float w0 = c1W1[c]       + c1W1[768 + c];
    float w1 = c1W1[256 + c] + c1W1[1024 + c];
    float w2 = c1W1[512 + c] + c1W1[1280 + c];
    float bv = c1b1[c];
    int i0 = (b - 1504) * 16;
#pragma unroll
    for (int r = 0; r < 16; ++r) {
      int i = i0 + r;
      float x = pos[3 * i], y = pos[3 * i + 1], z = pos[3 * i + 2];
      TU[(size_t)i * 256 + c] = fmaf(x, w0, fmaf(y, w1, fmaf(z, w2, bv)));
    }
  }
}

// ---------------------------------------------------------------------------
// kNN pass 1: thread = (target i, chunk ch). 16 smallest d2 VALUES (u32),
// 4x unrolled (batched LDS loads + key ILP), written contiguously per (ch,i).
// ---------------------------------------------------------------------------
__global__ __launch_bounds__(256) void knn_d2p1(const float4* __restrict__ pos4,
                                                unsigned* __restrict__ v) {
  __shared__ float4 cand[CH];
  int ch = blockIdx.x & (NCH - 1);
  int i  = (blockIdx.x >> 5) * 256 + threadIdx.x;
  cand[threadIdx.x] = pos4[ch * CH + threadIdx.x];
  __syncthreads();

  float4 p = pos4[i];
  U32INIT
  for (int jj = 0; jj < CH; jj += 4) {
    float4 c0 = cand[jj], c1 = cand[jj + 1], c2 = cand[jj + 2],
           c3 = cand[jj + 3];
    unsigned x0 = d2key(p, c0), x1 = d2key(p, c1);
    unsigned x2 = d2key(p, c2), x3 = d2key(p, c3);
    U32CHAIN(x0) U32CHAIN(x1) U32CHAIN(x2) U32CHAIN(x3)
  }
  uint4* dst = reinterpret_cast<uint4*>(v + ((size_t)ch * NPTS + i) * 16);
  dst[0] = make_uint4(b0, b1, b2, b3);
  dst[1] = make_uint4(b4, b5, b6, b7);
  dst[2] = make_uint4(b8, b9, b10, b11);
  dst[3] = make_uint4(b12, b13, b14, b15);
}

// ---------------------------------------------------------------------------
// kNN merge: one WAVE per target; 16 selection rounds over 32 sorted 16-lists
// (lane = half-chunk, 8 values). Exact global 16th-smallest -> T[i].
// ---------------------------------------------------------------------------
__global__ __launch_bounds__(256) void knn_merge(const unsigned* __restrict__ v,
                                                 unsigned* __restrict__ T,
                                                 unsigned* __restrict__ cnt) {
  int wv = threadIdx.x >> 6, lane = threadIdx.x & 63;
  int i = blockIdx.x * 4 + wv;
  int ch = lane >> 1, half = lane & 1;
  const uint4* src = reinterpret_cast<const uint4*>(
      v + ((size_t)ch * NPTS + i) * 16 + half * 8);
  uint4 a = src[0], b = src[1];
  unsigned r1 = a.y, r2 = a.z, r3 = a.w;
  unsigned r4 = b.x, r5 = b.y, r6 = b.z, r7 = b.w;
  unsigned h = a.x;
  int idx = 0;
  unsigned wmin = 0;
#pragma unroll
  for (int round = 0; round < 16; ++round) {
    unsigned m = h;
    m = min(m, (unsigned)__shfl_xor((int)m, 1));
    m = min(m, (unsigned)__shfl_xor((int)m, 2));
    m = min(m, (unsigned)__shfl_xor((int)m, 4));
    m = min(m, (unsigned)__shfl_xor((int)m, 8));
    m = min(m, (unsigned)__shfl_xor((int)m, 16));
    m = min(m, (unsigned)__shfl_xor((int)m, 32));
    wmin = m;
    u64 ball = __ballot(h == m);
    int src_lane = __ffsll(ball) - 1;
    if (lane == src_lane) {
      ++idx;
      h = idx == 1 ? r1 : idx == 2 ? r2 : idx == 3 ? r3 : idx == 4 ? r4 :
          idx == 5 ? r5 : idx == 6 ? r6 : idx == 7 ? r7 : 0xFFFFFFFFu;
    }
  }
  if (lane == 0) { T[i] = wmin; cnt[i] = 0; }
}

// ---------------------------------------------------------------------------
// kNN pass 2: 8x-unrolled re-scan (identical d2key bits); min8 guard, then
// rare qualifier path (d2 <= T) appends to the CAP-slot buffer.
// ---------------------------------------------------------------------------
__global__ __launch_bounds__(256) void knn_d2p2(const float4* __restrict__ pos4,
                                                const unsigned* __restrict__ T,
                                                unsigned* __restrict__ cnt,
                                                u64* __restrict__ cbuf) {
  __shared__ float4 cand[CH];
  int ch = blockIdx.x & (NCH - 1);
  int i  = (blockIdx.x >> 5) * 256 + threadIdx.x;
  cand[threadIdx.x] = pos4[ch * CH + threadIdx.x];
  __syncthreads();

  float4 p = pos4[i];
  unsigned Ti = T[i];
  int jb = ch * CH;
  for (int jj = 0; jj < CH; jj += 8) {
    unsigned k[8];
#pragma unroll
    for (int u = 0; u < 8; ++u) k[u] = d2key(p, cand[jj + u]);
    unsigned m = min(min(min(k[0], k[1]), min(k[2], k[3])),
                     min(min(k[4], k[5]), min(k[6], k[7])));
    if (m <= Ti) {
#pragma unroll
      for (int u = 0; u < 8; ++u) {
        if (k[u] <= Ti) {
          unsigned slot = atomicAdd(&cnt[i], 1u);
          if (slot < CAP)
            cbuf[(size_t)i * CAP + slot] =
                ((u64)k[u] << 32) | (unsigned)(jb + jj + u);
        }
      }
    }
  }
}

// ---------------------------------------------------------------------------
// kNN select: exact lexicographic (d2, idx) top-16 over the <=CAP qualifiers.
// ---------------------------------------------------------------------------
__global__ __launch_bounds__(256) void knn_select(const unsigned* __restrict__ cnt,
                                                  const u64* __restrict__ cbuf,
                                                  int* __restrict__ idx_out) {
  int i = blockIdx.x * 256 + threadIdx.x;
  int c = (int)min(cnt[i], (unsigned)CAP);
  KINIT
#pragma unroll 1
  for (int q = 0; q < c; ++q) {
    u64 key = cbuf[(size_t)i * CAP + q];
    if (key < k15) { KCHAIN }
  }
  int* o = idx_out + i * 16;
  o[0]=(int)(unsigned)k0;   o[1]=(int)(unsigned)k1;   o[2]=(int)(unsigned)k2;
  o[3]=(int)(unsigned)k3;   o[4]=(int)(unsigned)k4;   o[5]=(int)(unsigned)k5;
  o[6]=(int)(unsigned)k6;   o[7]=(int)(unsigned)k7;   o[8]=(int)(unsigned)k8;
  o[9]=(int)(unsigned)k9;   o[10]=(int)(unsigned)k10; o[11]=(int)(unsigned)k11;
  o[12]=(int)(unsigned)k12; o[13]=(int)(unsigned)k13; o[14]=(int)(unsigned)k14;
  o[15]=(int)(unsigned)k15;
}

// ---------------------------------------------------------------------------
// MFMA GEMM: out[M][NCOLS] = act(bf16(A[M][KDIM]) @ Wf + bias [+ pos@W1p]).
// ---------------------------------------------------------------------------
template <int NCOLS, int KDIM, int ACT, int ADDP>
__global__ __launch_bounds__(256) void gemm_mfma(
    const float* __restrict__ A,
    const short* __restrict__ wf,
    const float* __restrict__ bias,
    const float* __restrict__ pos,
    const float* __restrict__ W1p,
    float* __restrict__ out) {
  constexpr int KS = KDIM / 32;
  constexpr int NF = NCOLS / 64;
  __shared__ __align__(16) short As[32 * KDIM];

  int tid = threadIdx.x;
  int row0 = blockIdx.x * 32;

  {  // stage A: 32 rows x KDIM fp32 -> bf16, swizzled
    int row = tid & 31, wq = tid >> 5;
    const float* Ar = A + (size_t)(row0 + row) * KDIM;
#pragma unroll
    for (int q = 0; q < KDIM / 64; ++q) {
      int c0 = wq * 8 + q * 64;
      float4 a = *reinterpret_cast<const float4*>(Ar + c0);
      float4 b = *reinterpret_cast<const float4*>(Ar + c0 + 4);
      bf16x8 o;
      o[0] = f2bf(a.x); o[1] = f2bf(a.y); o[2] = f2bf(a.z); o[3] = f2bf(a.w);
      o[4] = f2bf(b.x); o[5] = f2bf(b.y); o[6] = f2bf(b.z); o[7] = f2bf(b.w);
      int byte = row * (KDIM * 2) + c0 * 2;
      byte ^= (row & 7) << 4;
      *reinterpret_cast<bf16x8*>(reinterpret_cast<char*>(As) + byte) = o;
    }
  }
  __syncthreads();

  int l = tid & 63, w = tid >> 6;
  int lhi = l >> 4, llo = l & 15;
  f32x4 zero = {0.f, 0.f, 0.f, 0.f};
  f32x4 acc[2][NF];
#pragma unroll
  for (int m = 0; m < 2; ++m)
#pragma unroll
    for (int n = 0; n < NF; ++n) acc[m][n] = zero;

  const bf16x8* WfV = reinterpret_cast<const bf16x8*>(wf);
#pragma unroll
  for (int ks = 0; ks < KS; ++ks) {
    bf16x8 af[2], bfr[NF];
#pragma unroll
    for (int m = 0; m < 2; ++m) {
      int r = m * 16 + llo;
      int byte = r * (KDIM * 2) + ks * 64 + lhi * 16;
      byte ^= (r & 7) << 4;
      af[m] = *reinterpret_cast<const bf16x8*>(
          reinterpret_cast<const char*>(As) + byte);
    }
#pragma unroll
    for (int n = 0; n < NF; ++n)
      bfr[n] = WfV[((w * NF + n) * KS + ks) * 64 + l];
#pragma unroll
    for (int m = 0; m < 2; ++m)
#pragma unroll
      for (int n = 0; n < NF; ++n)
        acc[m][n] = __builtin_amdgcn_mfma_f32_16x16x32_bf16(af[m], bfr[n],
                                                            acc[m][n], 0, 0, 0);
  }

  int cc[NF];
  float bv[NF], u0[NF], u1[NF], u2[NF];
#pragma unroll
  for (int n = 0; n < NF; ++n) {
    cc[n] = (w * NF + n) * 16 + llo;
    bv[n] = bias[cc[n]];
    if constexpr (ADDP) {
      u0[n] = W1p[cc[n]];
      u1[n] = W1p[NCOLS + cc[n]];
      u2[n] = W1p[2 * NCOLS + cc[n]];
    } else { u0[n] = u1[n] = u2[n] = 0.f; }
  }
#pragma unroll
  for (int m = 0; m < 2; ++m)
#pragma unroll
    for (int j = 0; j < 4; ++j) {
      int r = row0 + m * 16 + lhi * 4 + j;
      float px = 0.f, py = 0.f, pz = 0.f;
      if constexpr (ADDP) { px = pos[3*r]; py = pos[3*r+1]; pz = pos[3*r+2]; }
#pragma unroll
      for (int n = 0; n < NF; ++n) {
        float v = acc[m][n][j] + bv[n];
        if constexpr (ADDP) v += px * u0[n] + py * u1[n] + pz * u2[n];
        if (ACT == 1) v = fmaxf(v, 0.0f);
        out[(size_t)r * NCOLS + cc[n]] = v;
      }
    }
}

// ---------------------------------------------------------------------------
// MFMA conv: block = 4 targets (64 rows = 4 x 16 nbrs) x 256 cols, K=256.
// ---------------------------------------------------------------------------
__global__ __launch_bounds__(256) void conv_mfma(
    const float* __restrict__ TU,
    const float* __restrict__ pos,
    const int* __restrict__ idx,
    const float* __restrict__ W1p,
    const short* __restrict__ w2f,
    const float* __restrict__ b2,
    float* __restrict__ hout) {
  __shared__ __align__(16) short m1s[64 * 256];
  __shared__ float Ub[4][256];
  __shared__ int js[64];

  int tid = threadIdx.x;
  int t0 = blockIdx.x * 4;
  if (tid < 64) js[tid] = idx[(t0 + (tid >> 4)) * 16 + (tid & 15)];
#pragma unroll
  for (int q = 0; q < 4; ++q) {
    int e = tid + 256 * q;
    int tg = e >> 8, c = e & 255;
    float x = pos[3 * (t0 + tg)], y = pos[3 * (t0 + tg) + 1],
          z = pos[3 * (t0 + tg) + 2];
    Ub[tg][c] = x * W1p[c] + y * W1p[256 + c] + z * W1p[512 + c];
  }
  __syncthreads();

  {
    int row = tid & 63;
    int wq = tid >> 6;
    int jrow = js[row];
    const float* TUj = TU + (size_t)jrow * 256;
    const float* Ui = &Ub[row >> 4][0];
#pragma unroll
    for (int q = 0; q < 8; ++q) {
      int c0 = wq * 8 + q * 32;
      float4 a = *reinterpret_cast<const float4*>(TUj + c0);
      float4 b = *reinterpret_cast<const float4*>(TUj + c0 + 4);
      float4 ua = *reinterpret_cast<const float4*>(Ui + c0);
      float4 ub = *reinterpret_cast<const float4*>(Ui + c0 + 4);
      bf16x8 o;
      o[0] = f2bf(fmaxf(a.x - ua.x, 0.f));
      o[1] = f2bf(fmaxf(a.y - ua.y, 0.f));
      o[2] = f2bf(fmaxf(a.z - ua.z, 0.f));
      o[3] = f2bf(fmaxf(a.w - ua.w, 0.f));
      o[4] = f2bf(fmaxf(b.x - ub.x, 0.f));
      o[5] = f2bf(fmaxf(b.y - ub.y, 0.f));
      o[6] = f2bf(fmaxf(b.z - ub.z, 0.f));
      o[7] = f2bf(fmaxf(b.w - ub.w, 0.f));
      int byte = row * 512 + c0 * 2;
      byte ^= (row & 7) << 4;
      *reinterpret_cast<bf16x8*>(reinterpret_cast<char*>(m1s) + byte) = o;
    }
  }
  __syncthreads();

  int l = tid & 63, w = tid >> 6;
  int lhi = l >> 4, llo = l & 15;
  f32x4 zero = {0.f, 0.f, 0.f, 0.f};
  f32x4 acc[4][4];
#pragma unroll
  for (int m = 0; m < 4; ++m)
#pragma unroll
    for (int n = 0; n < 4; ++n) acc[m][n] = zero;

  const bf16x8* Wf = reinterpret_cast<const bf16x8*>(w2f);
#pragma unroll
  for (int ks = 0; ks < 8; ++ks) {
    int k0 = ks * 32;
    bf16x8 af[4], bfr[4];
#pragma unroll
    for (int m = 0; m < 4; ++m) {
      int r = m * 16 + llo;
      int byte = r * 512 + k0 * 2 + lhi * 16;
      byte ^= (r & 7) << 4;
      af[m] = *reinterpret_cast<const bf16x8*>(
          reinterpret_cast<const char*>(m1s) + byte);
    }
#pragma unroll
    for (int n = 0; n < 4; ++n)
      bfr[n] = Wf[((w * 4 + n) * 8 + ks) * 64 + l];
#pragma unroll
    for (int m = 0; m < 4; ++m)
#pragma unroll
      for (int n = 0; n < 4; ++n)
        acc[m][n] = __builtin_amdgcn_mfma_f32_16x16x32_bf16(af[m], bfr[n],
                                                            acc[m][n], 0, 0, 0);
  }

#pragma unroll
  for (int m = 0; m < 4; ++m)
#pragma unroll
    for (int n = 0; n < 4; ++n) {
      float v = fmaxf(fmaxf(acc[m][n][0], acc[m][n][1]),
                      fmaxf(acc[m][n][2], acc[m][n][3]));
      v = fmaxf(v, __shfl_xor(v, 16));
      v = fmaxf(v, __shfl_xor(v, 32));
      if (lhi == 0) {
        int c = w * 64 + n * 16 + llo;
        hout[(size_t)(t0 + m) * CDIM + c] = fmaxf(v + b2[c], 0.0f);
      }
    }
}

// ---------------------------------------------------------------------------
// Final layer: out[r] = sigmoid(h2[r] . w3 + b3); one wave per row.
// ---------------------------------------------------------------------------
__global__ __launch_bounds__(64) void final_k(const float* __restrict__ h2,
                                              const float* __restrict__ w3,
                                              const float* __restrict__ b3,
                                              float* __restrict__ out) {
  int r = blockIdx.x, l = threadIdx.x;
  float s = h2[(size_t)r * HDIM + l] * w3[l] +
            h2[(size_t)r * HDIM + 64 + l] * w3[64 + l];
#pragma unroll
  for (int o = 32; o > 0; o >>= 1) s += __shfl_down(s, o);
  if (l == 0) out[r] = 1.0f / (1.0f + expf(-(s + b3[0])));
}

extern "C" void kernel_launch(void* const* d_in, const int* in_sizes, int n_in,
                              void* d_out, int out_size, void* d_ws,
                              size_t ws_size, hipStream_t stream) {
  const float* pos   = (const float*)d_in[0];
  const float* c1_W1 = (const float*)d_in[1];
  const float* c1_b1 = (const float*)d_in[2];
  const float* c1_W2 = (const float*)d_in[3];
  const float* c1_b2 = (const float*)d_in[4];
  const float* c2_W1 = (const float*)d_in[5];
  const float* c2_b1 = (const float*)d_in[6];
  const float* c2_W2 = (const float*)d_in[7];
  const float* c2_b2 = (const float*)d_in[8];
  const float* c3_W1 = (const float*)d_in[9];
  const float* c3_b1 = (const float*)d_in[10];
  const float* c3_W2 = (const float*)d_in[11];
  const float* c3_b2 = (const float*)d_in[12];
  const float* h_W1  = (const float*)d_in[13];
  const float* h_b1  = (const float*)d_in[14];
  const float* h_W2  = (const float*)d_in[15];
  const float* h_b2  = (const float*)d_in[16];
  const float* h_W3  = (const float*)d_in[17];
  const float* h_b3  = (const float*)d_in[18];
  float* out = (float*)d_out;

  char* w = (char*)d_ws;
  const size_t MB = 1 << 20;
  const size_t KB = 1 << 10;
  int*      p_idx  = (int*)w;                           // 512K
  float4*   p_pos4 = (float4*)(w + 512 * KB);           // 128K
  unsigned* p_T    = (unsigned*)(w + 640 * KB);         // 32K
  unsigned* p_cnt  = (unsigned*)(w + 672 * KB);         // 32K
  short*    p_w2f1 = (short*)(w + 704 * KB);            // 128K
  short*    p_w2f2 = (short*)(w + 832 * KB);            // 128K
  short*    p_w2f3 = (short*)(w + 960 * KB);            // 128K
  short*    p_wc2a = (short*)(w + 1088 * KB);           // 128K
  short*    p_wc3a = (short*)(w + 1216 * KB);           // 128K
  short*    p_whW1 = (short*)(w + 1344 * KB);           // 64K
  short*    p_whW2 = (short*)(w + 1408 * KB);           // 32K
  u64*      p_cbuf = (u64*)(w + 1536 * KB);             // 3MB
  float*    p_TU   = (float*)(w + 5 * MB);              // 8MB  [5,13)
  unsigned* p_v    = (unsigned*)(w + 13 * MB);          // 16MB [13,29) knn only
  float*    p_hA   = (float*)(w + 13 * MB);             // 8MB  (v dead)
  float*    p_hB   = (float*)(w + 21 * MB);             // 8MB  (v dead)
  float*    p_c1   = (float*)(w + 5 * MB);              // 4MB  (TU dead)
  float*    p_c2   = (float*)(w + 9 * MB);              // 4MB

  // fused prep: weights, pos4, conv1 TU (TU region untouched by kNN)
  prep_all<<<2016, 256, 0, stream>>>(
      c1_W2, c2_W2, c3_W2, c2_W1, c3_W1, h_W1, h_W2,
      p_w2f1, p_w2f2, p_w2f3, p_wc2a, p_wc3a, p_whW1, p_whW2,
      pos, p_pos4, c1_W1, c1_b1, p_TU);

  // kNN: two-pass exact top-16 (wave-parallel merge)
  knn_d2p1<<<(NPTS / 256) * NCH, 256, 0, stream>>>(p_pos4, p_v);
  knn_merge<<<NPTS / 4, 256, 0, stream>>>(p_v, p_T, p_cnt);
  knn_d2p2<<<(NPTS / 256) * NCH, 256, 0, stream>>>(p_pos4, p_T, p_cnt, p_cbuf);
  knn_select<<<NPTS / 256, 256, 0, stream>>>(p_cnt, p_cbuf, p_idx);

  // conv1
  conv_mfma<<<NPTS / 4, 256, 0, stream>>>(p_TU, pos, p_idx, c1_W1 + 3 * 256,
                                          p_w2f1, c1_b2, p_hA);
  // conv2
  gemm_mfma<256, 256, 0, 1><<<NPTS / 32, 256, 0, stream>>>(
      p_hA, p_wc2a, c2_b1, pos, c2_W1 + 256 * 256, p_TU);
  conv_mfma<<<NPTS / 4, 256, 0, stream>>>(p_TU, pos, p_idx, c2_W1 + 256 * 256,
                                          p_w2f2, c2_b2, p_hB);
  // conv3
  gemm_mfma<256, 256, 0, 1><<<NPTS / 32, 256, 0, stream>>>(
      p_hB, p_wc3a, c3_b1, pos, c3_W1 + 256 * 256, p_TU);
  conv_mfma<<<NPTS / 4, 256, 0, stream>>>(p_TU, pos, p_idx, c3_W1 + 256 * 256,
                                          p_w2f3, c3_b2, p_hA);
  // classifier
  gemm_mfma<128, 256, 1, 0><<<NPTS / 32, 256, 0, stream>>>(
      p_hA, p_whW1, h_b1, nullptr, nullptr, p_c1);
  gemm_mfma<128, 128, 1, 0><<<NPTS / 32, 256, 0, stream>>>(
      p_c1, p_whW2, h_b2, nullptr, nullptr, p_c2);
  final_k<<<NPTS, 64, 0, stream>>>(p_c2, h_W3, h_b3, out);

  (void)in_sizes; (void)n_in; (void)out_size; (void)ws_size;
}